// Round 1
// baseline (1993.193 us; speedup 1.0000x reference)
//
#include <hip/hip_runtime.h>
#include <math.h>

#define S_TOT 16384
#define BATCH 4
#define DIN 512
#define NH 8
#define DK 64
#define SEGF 2048
#define SEGS 512          // selected tokens per full segment
#define NSEG 8            // full segments per batch
#define NUSE 2            // inner segments that can affect the (padded) output
#define MROWS (BATCH*NUSE*SEGS)   // 4096 rows through attention/MLP

// ---------------- scores = x @ w_samp + b ----------------
__global__ __launch_bounds__(256) void scores_kernel(
    const float* __restrict__ x, const float* __restrict__ w,
    const float* __restrict__ bsamp, float* __restrict__ out)
{
  int tok  = blockIdx.x * 4 + (threadIdx.x >> 6);
  int lane = threadIdx.x & 63;
  const float* xr = x + (size_t)tok * DIN;
  float p = 0.f;
  #pragma unroll
  for (int it = 0; it < 8; ++it)
    p += xr[lane + it*64] * w[lane + it*64];
  #pragma unroll
  for (int off = 32; off > 0; off >>= 1) p += __shfl_down(p, off);
  if (lane == 0) out[tok] = p + bsamp[0];
}

// ---------------- top-512 per (b, full segment), stable by index ----------------
__global__ __launch_bounds__(256) void topk_kernel(
    const float* __restrict__ scores, int* __restrict__ flat,
    int* __restrict__ inv, float* __restrict__ maskOut)
{
  int b = blockIdx.x >> 3, g = blockIdx.x & 7;
  __shared__ float sc[SEGF];
  __shared__ int pfx[256];
  int tid = threadIdx.x;
  const float* src = scores + (size_t)b*S_TOT + (size_t)g*SEGF;
  float4 v0 = *(const float4*)(src + tid*8);
  float4 v1 = *(const float4*)(src + tid*8 + 4);
  *(float4*)&sc[tid*8]     = v0;
  *(float4*)&sc[tid*8 + 4] = v1;
  __syncthreads();
  float mine[8] = {v0.x,v0.y,v0.z,v0.w,v1.x,v1.y,v1.z,v1.w};
  int cnt[8] = {0,0,0,0,0,0,0,0};
  int i0 = tid*8;
  for (int j = 0; j < SEGF; ++j) {
    float v = sc[j];
    #pragma unroll
    for (int l = 0; l < 8; ++l)
      cnt[l] += (v > mine[l] || (v == mine[l] && j < i0 + l)) ? 1 : 0;
  }
  int flg[8]; int ls = 0;
  #pragma unroll
  for (int l = 0; l < 8; ++l) { flg[l] = (cnt[l] < SEGS) ? 1 : 0; ls += flg[l]; }
  pfx[tid] = ls;
  __syncthreads();
  if (tid == 0) {
    int run = 0;
    for (int t = 0; t < 256; ++t) { int tmp = pfx[t]; pfx[t] = run; run += tmp; }
  }
  __syncthreads();
  int pos = pfx[tid];
  #pragma unroll
  for (int l = 0; l < 8; ++l) {
    int i = i0 + l;
    maskOut[(size_t)b*S_TOT + (size_t)g*SEGF + i] = flg[l] ? 1.0f : 0.0f;
    if (g < NUSE) inv[b*(NUSE*SEGF) + g*SEGF + i] = flg[l] ? (g*SEGS + pos) : -1;
    if (flg[l]) {
      flat[b*(NSEG*SEGS) + g*SEGS + pos] = g*SEGF + i;
      pos++;
    }
  }
}

// ---------------- generic fp32 tiled GEMM: C = act(A@B + bias) ----------------
// 64x64 tile, BK=16, 256 threads, 4x4 per thread. Optional row-gather on A.
__global__ __launch_bounds__(256) void gemm64(
    const float* __restrict__ A, int lda,
    const float* __restrict__ Bm, int ldb,
    const float* __restrict__ bias,
    float* __restrict__ C, int ldc,
    int M, int N, int K,
    const int* __restrict__ gidx, int act)
{
  __shared__ float As[16][64];
  __shared__ float Bs[16][64];
  int tid = threadIdx.x;
  int tx = tid & 15, ty = tid >> 4;
  int bn = blockIdx.x * 64, bm = blockIdx.y * 64;
  int mload = tid >> 2;          // 0..63
  int kk4   = (tid & 3) * 4;     // 0,4,8,12
  int row = bm + mload;
  const float* asrc;
  if (gidx) {
    int bb = row >> 10;          // row / 1024
    int ii = row & 1023;
    asrc = A + ((size_t)(bb * S_TOT + gidx[bb * (NSEG*SEGS) + ii])) * (size_t)lda;
  } else {
    asrc = A + (size_t)row * lda;
  }
  int cload = (tid & 15) * 4;
  int kkb   = tid >> 4;
  float acc[4][4] = {};
  for (int k0 = 0; k0 < K; k0 += 16) {
    float4 av = *(const float4*)(asrc + k0 + kk4);
    As[kk4+0][mload] = av.x; As[kk4+1][mload] = av.y;
    As[kk4+2][mload] = av.z; As[kk4+3][mload] = av.w;
    *(float4*)&Bs[kkb][cload] = *(const float4*)(Bm + (size_t)(k0+kkb)*ldb + bn + cload);
    __syncthreads();
    #pragma unroll
    for (int kk = 0; kk < 16; ++kk) {
      float4 a  = *(const float4*)&As[kk][ty*4];
      float4 bv = *(const float4*)&Bs[kk][tx*4];
      acc[0][0] += a.x*bv.x; acc[0][1] += a.x*bv.y; acc[0][2] += a.x*bv.z; acc[0][3] += a.x*bv.w;
      acc[1][0] += a.y*bv.x; acc[1][1] += a.y*bv.y; acc[1][2] += a.y*bv.z; acc[1][3] += a.y*bv.w;
      acc[2][0] += a.z*bv.x; acc[2][1] += a.z*bv.y; acc[2][2] += a.z*bv.z; acc[2][3] += a.z*bv.w;
      acc[3][0] += a.w*bv.x; acc[3][1] += a.w*bv.y; acc[3][2] += a.w*bv.z; acc[3][3] += a.w*bv.w;
    }
    __syncthreads();
  }
  #pragma unroll
  for (int i = 0; i < 4; ++i) {
    #pragma unroll
    for (int j = 0; j < 4; ++j) {
      float v = acc[i][j];
      int col = bn + tx*4 + j;
      if (bias) v += bias[col];
      if (act == 1) v = 0.5f * v * (1.0f + erff(v * 0.70710678118f));
      C[(size_t)(bm + ty*4 + i) * ldc + col] = v;
    }
  }
}

// ---------------- M0 = sk(seg0)^T @ v(seg0),  z0 = sum_s sk(seg0) ----------------
__global__ __launch_bounds__(256) void memsum_kernel(
    const float* __restrict__ k, const float* __restrict__ v,
    float* __restrict__ M0, float* __restrict__ z0)
{
  int b = blockIdx.x >> 3, h = blockIdx.x & 7;
  __shared__ float Ks[64][64];
  __shared__ float Vs[64][64];
  int tid = threadIdx.x;
  int tx = tid & 15, ty = tid >> 4;
  int d4 = (tid & 15) * 4, sl = tid >> 4;
  size_t base = (size_t)(b * (NUSE*SEGS)) * DIN + h * DK;   // segment 0 rows
  float acc[4][4] = {};
  float zacc[4] = {0.f,0.f,0.f,0.f};
  for (int c = 0; c < 8; ++c) {
    #pragma unroll
    for (int l = 0; l < 4; ++l) {
      int r = c*64 + sl + l*16;
      float4 kv = *(const float4*)(k + base + (size_t)r*DIN + d4);
      kv.x = kv.x > 0.f ? kv.x + 1.f : expf(kv.x);   // elu(k)+1
      kv.y = kv.y > 0.f ? kv.y + 1.f : expf(kv.y);
      kv.z = kv.z > 0.f ? kv.z + 1.f : expf(kv.z);
      kv.w = kv.w > 0.f ? kv.w + 1.f : expf(kv.w);
      *(float4*)&Ks[sl + l*16][d4] = kv;
      *(float4*)&Vs[sl + l*16][d4] = *(const float4*)(v + base + (size_t)r*DIN + d4);
    }
    __syncthreads();
    for (int s2 = 0; s2 < 64; ++s2) {
      float4 a  = *(const float4*)&Ks[s2][ty*4];
      float4 bb = *(const float4*)&Vs[s2][tx*4];
      acc[0][0] += a.x*bb.x; acc[0][1] += a.x*bb.y; acc[0][2] += a.x*bb.z; acc[0][3] += a.x*bb.w;
      acc[1][0] += a.y*bb.x; acc[1][1] += a.y*bb.y; acc[1][2] += a.y*bb.z; acc[1][3] += a.y*bb.w;
      acc[2][0] += a.z*bb.x; acc[2][1] += a.z*bb.y; acc[2][2] += a.z*bb.z; acc[2][3] += a.z*bb.w;
      acc[3][0] += a.w*bb.x; acc[3][1] += a.w*bb.y; acc[3][2] += a.w*bb.z; acc[3][3] += a.w*bb.w;
      if (tx == 0) { zacc[0]+=a.x; zacc[1]+=a.y; zacc[2]+=a.z; zacc[3]+=a.w; }
    }
    __syncthreads();
  }
  size_t mb = (size_t)(b*NH + h) * 4096;
  #pragma unroll
  for (int i = 0; i < 4; ++i)
    #pragma unroll
    for (int j = 0; j < 4; ++j)
      M0[mb + (size_t)(ty*4 + i)*64 + tx*4 + j] = acc[i][j];
  if (tx == 0) {
    #pragma unroll
    for (int i = 0; i < 4; ++i) z0[(b*NH + h)*64 + ty*4 + i] = zacc[i];
  }
}

// ---------------- attention per (b, h, inner-seg, half): softmax + memory ----------------
__global__ __launch_bounds__(256) void attn_kernel(
    const float* __restrict__ q, const float* __restrict__ k, const float* __restrict__ v,
    const float* __restrict__ M0, const float* __restrict__ z0,
    const float* __restrict__ betas, float* __restrict__ attout)
{
  int t = blockIdx.x;
  int sub = t & 1;
  int g   = (t >> 1) & 1;
  int h   = (t >> 2) & 7;
  int b   = t >> 5;
  __shared__ float Ks[64][64];
  __shared__ float Vs[64][64];
  __shared__ float zbuf[64];
  __shared__ float gbuf[64];
  int tid = threadIdx.x;
  if (tid < 64) gbuf[tid] = 1.f / (1.f + expf(-betas[h*64 + tid]));  // sigmoid gate
  int s = sub * 256 + tid;
  size_t rowbase = (size_t)(b * (NUSE*SEGS) + g * SEGS + s) * DIN + h * DK;
  float qr[64];
  #pragma unroll
  for (int d4 = 0; d4 < 64; d4 += 4) {
    float4 qv = *(const float4*)(q + rowbase + d4);
    qr[d4] = qv.x; qr[d4+1] = qv.y; qr[d4+2] = qv.z; qr[d4+3] = qv.w;
  }
  const float scale = 0.125f;   // 1/sqrt(64)
  int d4l = (tid & 15) * 4, sl = tid >> 4;
  size_t kvbase = (size_t)(b * (NUSE*SEGS) + g * SEGS) * DIN + h * DK;
  // pass 1: row max of scaled scores
  float m = -1e30f;
  for (int c = 0; c < 8; ++c) {
    #pragma unroll
    for (int l = 0; l < 4; ++l) {
      int r = c*64 + sl + l*16;
      *(float4*)&Ks[sl + l*16][d4l] = *(const float4*)(k + kvbase + (size_t)r*DIN + d4l);
    }
    __syncthreads();
    for (int j = 0; j < 64; ++j) {
      float dot = 0.f;
      #pragma unroll
      for (int d = 0; d < 64; ++d) dot += qr[d] * Ks[j][d];
      m = fmaxf(m, dot * scale);
    }
    __syncthreads();
  }
  // pass 2: exp-sum + P@V
  float acc[64];
  #pragma unroll
  for (int d = 0; d < 64; ++d) acc[d] = 0.f;
  float lsum = 0.f;
  for (int c = 0; c < 8; ++c) {
    #pragma unroll
    for (int l = 0; l < 4; ++l) {
      int r = c*64 + sl + l*16;
      *(float4*)&Ks[sl + l*16][d4l] = *(const float4*)(k + kvbase + (size_t)r*DIN + d4l);
      *(float4*)&Vs[sl + l*16][d4l] = *(const float4*)(v + kvbase + (size_t)r*DIN + d4l);
    }
    __syncthreads();
    for (int j = 0; j < 64; ++j) {
      float dot = 0.f;
      #pragma unroll
      for (int d = 0; d < 64; ++d) dot += qr[d] * Ks[j][d];
      float p = expf(dot * scale - m);
      lsum += p;
      #pragma unroll
      for (int d = 0; d < 64; ++d) acc[d] += p * Vs[j][d];
    }
    __syncthreads();
  }
  float invl = 1.0f / lsum;
  // phase B: memory attention (seg 0 has mem=0 -> att_mem = 0)
  if (g > 0) {
    for (int idx = tid; idx < 4096; idx += 256)
      ((float*)Ks)[idx] = M0[(size_t)(b*NH + h) * 4096 + idx];
    if (tid < 64) zbuf[tid] = 1.0f/64.0f + z0[(b*NH + h)*64 + tid];
  }
  __syncthreads();
  #pragma unroll
  for (int d = 0; d < 64; ++d) qr[d] = qr[d] > 0.f ? qr[d] + 1.f : expf(qr[d]);  // sq = elu(q)+1
  float invden = 0.f;
  if (g > 0) {
    float den = 0.f;
    #pragma unroll
    for (int d = 0; d < 64; ++d) den += qr[d] * zbuf[d];
    invden = 1.0f / den;
  }
  #pragma unroll
  for (int dv = 0; dv < 64; ++dv) {
    float am = 0.f;
    if (g > 0) {
      float num = 0.f;
      #pragma unroll
      for (int d = 0; d < 64; ++d) num += qr[d] * Ks[d][dv];
      am = num * invden;
    }
    float gt = gbuf[dv];
    attout[rowbase + dv] = gt * am + (1.f - gt) * acc[dv] * invl;
  }
}

// ---------------- final: x_out = (x + scatter(h)) * pad, zeros for s>=4096 ----------------
__global__ __launch_bounds__(256) void final_kernel(
    const float* __restrict__ x, const int* __restrict__ inv,
    const float* __restrict__ hm, float* __restrict__ outX)
{
  int row  = blockIdx.x * 4 + (threadIdx.x >> 6);
  int lane = threadIdx.x & 63;
  int b = row >> 14;            // / S_TOT
  int s = row & (S_TOT - 1);
  size_t base = (size_t)row * DIN + lane * 8;
  if (s >= NUSE * SEGF) {
    float4 z = make_float4(0.f,0.f,0.f,0.f);
    *(float4*)(outX + base)     = z;
    *(float4*)(outX + base + 4) = z;
    return;
  }
  float4 a0 = *(const float4*)(x + base);
  float4 a1 = *(const float4*)(x + base + 4);
  int i = inv[b * (NUSE*SEGF) + s];
  if (i >= 0) {
    size_t hb = (size_t)(b * (NUSE*SEGS) + i) * DIN + lane * 8;
    float4 h0 = *(const float4*)(hm + hb);
    float4 h1 = *(const float4*)(hm + hb + 4);
    a0.x += h0.x; a0.y += h0.y; a0.z += h0.z; a0.w += h0.w;
    a1.x += h1.x; a1.y += h1.y; a1.z += h1.z; a1.w += h1.w;
  }
  *(float4*)(outX + base)     = a0;
  *(float4*)(outX + base + 4) = a1;
}

extern "C" void kernel_launch(void* const* d_in, const int* in_sizes, int n_in,
                              void* d_out, int out_size, void* d_ws, size_t ws_size,
                              hipStream_t stream) {
  (void)in_sizes; (void)n_in; (void)out_size; (void)ws_size;
  const float* x      = (const float*)d_in[0];
  const float* w_samp = (const float*)d_in[1];
  const float* b_samp = (const float*)d_in[2];
  const float* w_q    = (const float*)d_in[3];
  const float* w_k    = (const float*)d_in[4];
  const float* w_v    = (const float*)d_in[5];
  const float* w_o    = (const float*)d_in[6];
  const float* betas  = (const float*)d_in[7];
  const float* w1     = (const float*)d_in[8];
  const float* b1     = (const float*)d_in[9];
  const float* w2     = (const float*)d_in[10];
  const float* b2     = (const float*)d_in[11];

  float* outX      = (float*)d_out;                                  // [B,S,DIN]
  float* outMask   = outX + (size_t)BATCH * S_TOT * DIN;             // [B*S,1]
  float* outScores = outMask + (size_t)BATCH * S_TOT;                // [B*S,1]

  char* ws = (char*)d_ws;
  int*   flat = (int*)(ws);                         // [B][4096]           64 KB
  int*   inv  = (int*)(ws + (64<<10));              // [B][4096]           64 KB
  float* M0   = (float*)(ws + (128<<10));           // [B][H][64][64]     512 KB
  float* z0   = (float*)(ws + (128<<10) + (512<<10)); // [B][H][64]         8 KB
  float* R0   = (float*)(ws + ((size_t)1<<20));     // h_attn / h_mlp       8 MB
  float* qb   = (float*)(ws + ((size_t)9<<20));     // q                    8 MB
  float* kb   = (float*)(ws + ((size_t)17<<20));    // k                    8 MB
  float* vb   = (float*)(ws + ((size_t)25<<20));    // v                    8 MB
  float* att  = (float*)(ws + ((size_t)33<<20));    // att                  8 MB
  float* hidden = qb;                               // overlays q..att     32 MB

  scores_kernel<<<(BATCH*S_TOT)/4, 256, 0, stream>>>(x, w_samp, b_samp, outScores);
  topk_kernel<<<BATCH*NSEG, 256, 0, stream>>>(outScores, flat, inv, outMask);

  // QKV projections on the 4096 routed rows (gather fused)
  gemm64<<<dim3(DIN/64, MROWS/64), 256, 0, stream>>>(x, DIN, w_q, DIN, nullptr, qb, DIN,
                                                     MROWS, DIN, DIN, flat, 0);
  gemm64<<<dim3(DIN/64, MROWS/64), 256, 0, stream>>>(x, DIN, w_k, DIN, nullptr, kb, DIN,
                                                     MROWS, DIN, DIN, flat, 0);
  gemm64<<<dim3(DIN/64, MROWS/64), 256, 0, stream>>>(x, DIN, w_v, DIN, nullptr, vb, DIN,
                                                     MROWS, DIN, DIN, flat, 0);

  memsum_kernel<<<BATCH*NH, 256, 0, stream>>>(kb, vb, M0, z0);
  attn_kernel<<<BATCH*NH*NUSE*2, 256, 0, stream>>>(qb, kb, vb, M0, z0, betas, att);

  // out projection
  gemm64<<<dim3(DIN/64, MROWS/64), 256, 0, stream>>>(att, DIN, w_o, DIN, nullptr, R0, DIN,
                                                     MROWS, DIN, DIN, nullptr, 0);
  // MLP
  gemm64<<<dim3(2048/64, MROWS/64), 256, 0, stream>>>(R0, DIN, w1, 2048, b1, hidden, 2048,
                                                      MROWS, 2048, DIN, nullptr, 1);
  gemm64<<<dim3(DIN/64, MROWS/64), 256, 0, stream>>>(hidden, 2048, w2, DIN, b2, R0, DIN,
                                                     MROWS, DIN, 2048, nullptr, 0);

  final_kernel<<<(BATCH*S_TOT)/4, 256, 0, stream>>>(x, inv, R0, outX);
}

// Round 2
// 1194.648 us; speedup vs baseline: 1.6684x; 1.6684x over previous
//
#include <hip/hip_runtime.h>
#include <math.h>

#define S_TOT 16384
#define BATCH 4
#define DIN 512
#define NH 8
#define DK 64
#define SEGF 2048
#define SEGS 512
#define NSEG 8
#define NUSE 2
#define MROWS (BATCH*NUSE*SEGS)   // 4096 rows through attention/MLP

typedef unsigned int u32;
typedef __attribute__((ext_vector_type(8))) short short8;
typedef __attribute__((ext_vector_type(4))) float f32x4;

__device__ __forceinline__ short f2b(float f) {
  u32 u = __float_as_uint(f);
  u32 r = u + 0x7fffu + ((u >> 16) & 1u);
  return (short)(r >> 16);
}
__device__ __forceinline__ float b2f_lo(u32 u) { return __uint_as_float(u << 16); }
__device__ __forceinline__ float b2f_hi(u32 u) { return __uint_as_float(u & 0xffff0000u); }

// ---------------- scores = x @ w_samp + b (fp32, exact for routing) ----------------
__global__ __launch_bounds__(256) void scores_kernel(
    const float* __restrict__ x, const float* __restrict__ w,
    const float* __restrict__ bsamp, float* __restrict__ out)
{
  int tok  = blockIdx.x * 4 + (threadIdx.x >> 6);
  int lane = threadIdx.x & 63;
  const float* xr = x + (size_t)tok * DIN;
  float p = 0.f;
  #pragma unroll
  for (int it = 0; it < 8; ++it)
    p += xr[lane + it*64] * w[lane + it*64];
  #pragma unroll
  for (int off = 32; off > 0; off >>= 1) p += __shfl_down(p, off);
  if (lane == 0) out[tok] = p + bsamp[0];
}

// ---------------- top-512 per (b, full segment), stable by index ----------------
__global__ __launch_bounds__(256) void topk_kernel(
    const float* __restrict__ scores, int* __restrict__ flat,
    int* __restrict__ inv, float* __restrict__ maskOut)
{
  int b = blockIdx.x >> 3, g = blockIdx.x & 7;
  __shared__ float sc[SEGF];
  __shared__ int pfx[256];
  int tid = threadIdx.x;
  const float* src = scores + (size_t)b*S_TOT + (size_t)g*SEGF;
  float4 v0 = *(const float4*)(src + tid*8);
  float4 v1 = *(const float4*)(src + tid*8 + 4);
  *(float4*)&sc[tid*8]     = v0;
  *(float4*)&sc[tid*8 + 4] = v1;
  __syncthreads();
  float mine[8] = {v0.x,v0.y,v0.z,v0.w,v1.x,v1.y,v1.z,v1.w};
  int cnt[8] = {0,0,0,0,0,0,0,0};
  int i0 = tid*8;
  for (int j = 0; j < SEGF; ++j) {
    float v = sc[j];
    #pragma unroll
    for (int l = 0; l < 8; ++l)
      cnt[l] += (v > mine[l] || (v == mine[l] && j < i0 + l)) ? 1 : 0;
  }
  int flg[8]; int ls = 0;
  #pragma unroll
  for (int l = 0; l < 8; ++l) { flg[l] = (cnt[l] < SEGS) ? 1 : 0; ls += flg[l]; }
  pfx[tid] = ls;
  __syncthreads();
  if (tid == 0) {
    int run = 0;
    for (int t = 0; t < 256; ++t) { int tmp = pfx[t]; pfx[t] = run; run += tmp; }
  }
  __syncthreads();
  int pos = pfx[tid];
  #pragma unroll
  for (int l = 0; l < 8; ++l) {
    int i = i0 + l;
    maskOut[(size_t)b*S_TOT + (size_t)g*SEGF + i] = flg[l] ? 1.0f : 0.0f;
    if (g < NUSE) inv[b*(NUSE*SEGF) + g*SEGF + i] = flg[l] ? (g*SEGS + pos) : -1;
    if (flg[l]) {
      flat[b*(NSEG*SEGS) + g*SEGS + pos] = g*SEGF + i;
      pos++;
    }
  }
}

// ---------------- transpose+cast weights: src[K][N] fp32 -> dst[(rowoff+n)][k] bf16 (ld=K)
__global__ __launch_bounds__(256) void transpose_cast(
    const float* __restrict__ src, short* __restrict__ dst,
    int K, int N, int rowoff)
{
  __shared__ float t[32][33];
  int tid = threadIdx.x;
  int txx = tid & 31, ty = tid >> 5;           // ty 0..7
  int n0 = blockIdx.x * 32, k0 = blockIdx.y * 32;
  #pragma unroll
  for (int r = 0; r < 4; ++r)
    t[ty + 8*r][txx] = src[(size_t)(k0 + ty + 8*r) * N + n0 + txx];
  __syncthreads();
  #pragma unroll
  for (int r = 0; r < 4; ++r)
    dst[(size_t)(rowoff + n0 + ty + 8*r) * K + k0 + txx] = f2b(t[txx][ty + 8*r]);
}

// ---------------- gather selected rows of x, cast to bf16: xsel[4096][512] ----------------
__global__ __launch_bounds__(256) void gather_cast(
    const float* __restrict__ x, const int* __restrict__ flat,
    short* __restrict__ xsel)
{
  int tok  = blockIdx.x * 4 + (threadIdx.x >> 6);   // 0..4095
  int lane = threadIdx.x & 63;
  int b = tok >> 10, i = tok & 1023;
  int gidx = flat[b * (NSEG*SEGS) + i];
  const float* srcp = x + ((size_t)(b * S_TOT + gidx)) * DIN + lane*8;
  float4 a0 = *(const float4*)srcp;
  float4 a1 = *(const float4*)(srcp + 4);
  uint4 o;
  o.x = (u32)(unsigned short)f2b(a0.x) | ((u32)(unsigned short)f2b(a0.y) << 16);
  o.y = (u32)(unsigned short)f2b(a0.z) | ((u32)(unsigned short)f2b(a0.w) << 16);
  o.z = (u32)(unsigned short)f2b(a1.x) | ((u32)(unsigned short)f2b(a1.y) << 16);
  o.w = (u32)(unsigned short)f2b(a1.z) | ((u32)(unsigned short)f2b(a1.w) << 16);
  *(uint4*)(xsel + (size_t)tok * DIN + lane*8) = o;
}

// ---------------- bf16 MFMA GEMM: C[M][N] = act(A[M][K] @ Bt[N][K]^T + bias) ----------------
template<int BM, int BN, int WM, int WN>
__global__ __launch_bounds__(256) void gemm_bf16(
    const short* __restrict__ A, const short* __restrict__ Bt,
    const float* __restrict__ bias, float* __restrict__ Cf,
    short* __restrict__ Cb, int M, int N, int K, int act)
{
  constexpr int BK = 32;
  constexpr int WAVES_N = BN / WN;
  constexpr int FM = WM / 16, FN = WN / 16;
  __shared__ short Al[BM * BK];
  __shared__ short Bl[BN * BK];
  const int tid = threadIdx.x;
  const int lane = tid & 63, wid = tid >> 6;
  const int wr = wid / WAVES_N, wc = wid % WAVES_N;
  const int bm = blockIdx.y * BM, bn = blockIdx.x * BN;
  const int srow = tid >> 2;            // 0..63
  const int scol = (tid & 3) * 8;       // element offset in 32-elem k-row

  f32x4 acc[FM][FN];
  #pragma unroll
  for (int i = 0; i < FM; ++i)
    #pragma unroll
    for (int j = 0; j < FN; ++j)
      #pragma unroll
      for (int e = 0; e < 4; ++e) acc[i][j][e] = 0.f;

  for (int k0 = 0; k0 < K; k0 += BK) {
    __syncthreads();
    #pragma unroll
    for (int i = 0; i < BM/64; ++i) {
      const short* gp = A + (size_t)(bm + i*64 + srow) * K + k0 + scol;
      __builtin_amdgcn_global_load_lds(
          (const __attribute__((address_space(1))) void*)gp,
          (__attribute__((address_space(3))) void*)&Al[(i*64 + srow)*BK + scol],
          16, 0, 0);
    }
    #pragma unroll
    for (int i = 0; i < BN/64; ++i) {
      const short* gp = Bt + (size_t)(bn + i*64 + srow) * K + k0 + scol;
      __builtin_amdgcn_global_load_lds(
          (const __attribute__((address_space(1))) void*)gp,
          (__attribute__((address_space(3))) void*)&Bl[(i*64 + srow)*BK + scol],
          16, 0, 0);
    }
    __syncthreads();
    short8 af[FM], bf_[FN];
    #pragma unroll
    for (int fm = 0; fm < FM; ++fm)
      af[fm] = *(const short8*)&Al[(wr*WM + fm*16 + (lane & 15))*BK + (lane >> 4)*8];
    #pragma unroll
    for (int fn = 0; fn < FN; ++fn)
      bf_[fn] = *(const short8*)&Bl[(wc*WN + fn*16 + (lane & 15))*BK + (lane >> 4)*8];
    #pragma unroll
    for (int fm = 0; fm < FM; ++fm)
      #pragma unroll
      for (int fn = 0; fn < FN; ++fn)
        acc[fm][fn] = __builtin_amdgcn_mfma_f32_16x16x32_bf16(af[fm], bf_[fn], acc[fm][fn], 0, 0, 0);
  }

  const int crow0 = (lane >> 4) * 4, ccol = lane & 15;
  #pragma unroll
  for (int fm = 0; fm < FM; ++fm) {
    #pragma unroll
    for (int fn = 0; fn < FN; ++fn) {
      #pragma unroll
      for (int j = 0; j < 4; ++j) {
        int r = bm + wr*WM + fm*16 + crow0 + j;
        int c = bn + wc*WN + fn*16 + ccol;
        float v = acc[fm][fn][j];
        if (bias) v += bias[c];
        if (act == 1) v = 0.5f * v * (1.0f + erff(v * 0.70710678118f));
        if (Cf) Cf[(size_t)r * N + c] = v;
        if (Cb) Cb[(size_t)r * N + c] = f2b(v);
      }
    }
  }
}

// ---------------- M0 = (elu(k)+1)^T @ v over seg0, z0 = sum ----------------
__global__ __launch_bounds__(256) void memsum_b(
    const short* __restrict__ qkv, float* __restrict__ M0, float* __restrict__ z0)
{
  int b = blockIdx.x >> 3, h = blockIdx.x & 7;
  __shared__ float Ks[64][64];
  __shared__ float Vs[64][64];
  int tid = threadIdx.x;
  int tx = tid & 15, ty = tid >> 4;
  int d4 = (tid & 15) * 4, sl = tid >> 4;
  float acc[4][4] = {};
  float zacc[4] = {0.f,0.f,0.f,0.f};
  for (int c = 0; c < 8; ++c) {
    #pragma unroll
    for (int l = 0; l < 4; ++l) {
      int r = c*64 + sl + l*16;
      size_t grow = (size_t)(b*1024 + r) * 1536 + h*64 + d4;
      uint2 kk = *(const uint2*)(qkv + grow + 512);
      float f0 = b2f_lo(kk.x), f1 = b2f_hi(kk.x), f2v = b2f_lo(kk.y), f3 = b2f_hi(kk.y);
      Ks[sl + l*16][d4+0] = f0 > 0.f ? f0 + 1.f : __expf(f0);
      Ks[sl + l*16][d4+1] = f1 > 0.f ? f1 + 1.f : __expf(f1);
      Ks[sl + l*16][d4+2] = f2v > 0.f ? f2v + 1.f : __expf(f2v);
      Ks[sl + l*16][d4+3] = f3 > 0.f ? f3 + 1.f : __expf(f3);
      uint2 vv = *(const uint2*)(qkv + grow + 1024);
      Vs[sl + l*16][d4+0] = b2f_lo(vv.x);
      Vs[sl + l*16][d4+1] = b2f_hi(vv.x);
      Vs[sl + l*16][d4+2] = b2f_lo(vv.y);
      Vs[sl + l*16][d4+3] = b2f_hi(vv.y);
    }
    __syncthreads();
    for (int s2 = 0; s2 < 64; ++s2) {
      float4 a  = *(const float4*)&Ks[s2][ty*4];
      float4 bb = *(const float4*)&Vs[s2][tx*4];
      acc[0][0] += a.x*bb.x; acc[0][1] += a.x*bb.y; acc[0][2] += a.x*bb.z; acc[0][3] += a.x*bb.w;
      acc[1][0] += a.y*bb.x; acc[1][1] += a.y*bb.y; acc[1][2] += a.y*bb.z; acc[1][3] += a.y*bb.w;
      acc[2][0] += a.z*bb.x; acc[2][1] += a.z*bb.y; acc[2][2] += a.z*bb.z; acc[2][3] += a.z*bb.w;
      acc[3][0] += a.w*bb.x; acc[3][1] += a.w*bb.y; acc[3][2] += a.w*bb.z; acc[3][3] += a.w*bb.w;
      if (tx == 0) { zacc[0]+=a.x; zacc[1]+=a.y; zacc[2]+=a.z; zacc[3]+=a.w; }
    }
    __syncthreads();
  }
  size_t mb = (size_t)(b*NH + h) * 4096;
  #pragma unroll
  for (int i = 0; i < 4; ++i)
    #pragma unroll
    for (int j = 0; j < 4; ++j)
      M0[mb + (size_t)(ty*4 + i)*64 + tx*4 + j] = acc[i][j];
  if (tx == 0) {
    #pragma unroll
    for (int i = 0; i < 4; ++i) z0[(b*NH + h)*64 + ty*4 + i] = zacc[i];
  }
}

// ---------------- attention: 512 blocks x 128 threads; 64 q/block, waves split keys ----
__global__ __launch_bounds__(128) void attn2(
    const short* __restrict__ qkv, const float* __restrict__ M0g,
    const float* __restrict__ z0g, const float* __restrict__ betas,
    short* __restrict__ att)
{
  __shared__ char smem[50944];
  int tid = threadIdx.x;
  int lane = tid & 63, kw = tid >> 6;
  int bx = blockIdx.x;
  int qc = bx & 7, g = (bx >> 3) & 1, h = (bx >> 4) & 7, b = bx >> 7;
  int qrow = b*1024 + g*512 + qc*64 + lane;

  // load my query row (bf16 -> f32)
  float qv[64];
  {
    const u32* qp = (const u32*)(qkv + (size_t)qrow*1536 + h*64);
    #pragma unroll
    for (int i = 0; i < 32; ++i) {
      u32 u = qp[i];
      qv[2*i]   = b2f_lo(u);
      qv[2*i+1] = b2f_hi(u);
    }
  }

  float* Kc = (float*)(smem + kw*16384);
  float* Vc = (float*)(smem + kw*16384 + 8192);
  float acc[64];
  #pragma unroll
  for (int d = 0; d < 64; ++d) acc[d] = 0.f;
  float lsum = 0.f;

  const size_t kvrow0 = (size_t)(b*1024 + g*512);
  for (int c = 0; c < 8; ++c) {
    int kbase = kw*256 + c*32;
    // stage 32 keys of K and V as fp32, conflict-free interleave
    #pragma unroll
    for (int i = 0; i < 8; ++i) {
      int j  = i*4 + (lane >> 4);
      int d0 = (lane & 15) * 4;
      size_t grow = (kvrow0 + kbase + j) * 1536 + h*64 + d0;
      uint2 kk = *(const uint2*)(qkv + grow + 512);
      int e = i*256 + lane*4;
      Kc[e+0] = b2f_lo(kk.x); Kc[e+1] = b2f_hi(kk.x);
      Kc[e+2] = b2f_lo(kk.y); Kc[e+3] = b2f_hi(kk.y);
      uint2 vv = *(const uint2*)(qkv + grow + 1024);
      Vc[e+0] = b2f_lo(vv.x); Vc[e+1] = b2f_hi(vv.x);
      Vc[e+2] = b2f_lo(vv.y); Vc[e+3] = b2f_hi(vv.y);
    }
    // consume 32 keys (wave-private region; compiler handles lgkmcnt)
    for (int j = 0; j < 32; ++j) {
      const float* kr = &Kc[j*64];
      float s = 0.f;
      #pragma unroll
      for (int d = 0; d < 64; ++d) s = fmaf(qv[d], kr[d], s);
      float p = __expf(s * 0.125f);
      lsum += p;
      const float* vr = &Vc[j*64];
      #pragma unroll
      for (int d = 0; d < 64; ++d) acc[d] = fmaf(p, vr[d], acc[d]);
    }
  }

  // exchange: ship the other wave's dv-half
  float* exch = (float*)(smem + 32768);        // [2][64][35]
  {
    float* exW = exch + (kw*64 + lane)*35;
    int oh = kw ^ 1;
    #pragma unroll
    for (int d = 0; d < 32; ++d) exW[d] = acc[oh*32 + d];
    exW[32] = lsum;
  }
  __syncthreads();
  // stage M0 (g=1) into dead K/V region of wave 0
  float* M0l = (float*)smem;                   // 16 KB
  float* zb  = (float*)(smem + 50688);         // 64 floats
  if (g) {
    const float* src = M0g + (size_t)(b*NH + h) * 4096;
    for (int i = tid; i < 1024; i += 128)
      *(float4*)&M0l[i*4] = *(const float4*)&src[i*4];
    if (tid < 64) zb[tid] = 0.015625f + z0g[(b*NH + h)*64 + tid];
  }
  __syncthreads();

  float acch[32]; float l2;
  {
    const float* exR = exch + ((kw^1)*64 + lane)*35;
    l2 = exR[32];
    #pragma unroll
    for (int d = 0; d < 32; ++d) acch[d] = acc[kw*32 + d] + exR[d];
  }
  float linv = 1.f / (lsum + l2);

  // sq = elu(q)+1
  float sq[64];
  #pragma unroll
  for (int d = 0; d < 64; ++d) {
    float qd = qv[d];
    sq[d] = qd > 0.f ? qd + 1.f : __expf(qd);
  }

  float num[32];
  #pragma unroll
  for (int dd = 0; dd < 32; ++dd) num[dd] = 0.f;
  if (g) {
    float den = 0.f;
    for (int d = 0; d < 64; ++d) {
      float s = sq[d];
      den = fmaf(s, zb[d], den);
      const float* mr = &M0l[d*64 + kw*32];
      #pragma unroll
      for (int dd = 0; dd < 32; ++dd) num[dd] = fmaf(s, mr[dd], num[dd]);
    }
    float dinv = 1.f / den;
    #pragma unroll
    for (int dd = 0; dd < 32; ++dd) num[dd] *= dinv;
  }

  // output: att[qrow][h*64 + kw*32 + dd]
  u32 ow[16];
  #pragma unroll
  for (int dd = 0; dd < 32; dd += 2) {
    float bt0 = betas[h*64 + kw*32 + dd];
    float bt1 = betas[h*64 + kw*32 + dd + 1];
    float g0 = 1.f / (1.f + __expf(-bt0));
    float g1 = 1.f / (1.f + __expf(-bt1));
    float v0 = g0 * num[dd]   + (1.f - g0) * acch[dd]   * linv;
    float v1 = g1 * num[dd+1] + (1.f - g1) * acch[dd+1] * linv;
    ow[dd>>1] = (u32)(unsigned short)f2b(v0) | ((u32)(unsigned short)f2b(v1) << 16);
  }
  u32* op = (u32*)(att + (size_t)qrow*512 + h*64 + kw*32);
  #pragma unroll
  for (int i = 0; i < 4; ++i)
    *(uint4*)(op + i*4) = make_uint4(ow[i*4], ow[i*4+1], ow[i*4+2], ow[i*4+3]);
}

// ---------------- final: x_out = (x + scatter(h)) * pad ----------------
__global__ __launch_bounds__(256) void final_kernel(
    const float* __restrict__ x, const int* __restrict__ inv,
    const float* __restrict__ hm, float* __restrict__ outX)
{
  int row  = blockIdx.x * 4 + (threadIdx.x >> 6);
  int lane = threadIdx.x & 63;
  int b = row >> 14;
  int s = row & (S_TOT - 1);
  size_t base = (size_t)row * DIN + lane * 8;
  if (s >= NUSE * SEGF) {
    float4 z = make_float4(0.f,0.f,0.f,0.f);
    *(float4*)(outX + base)     = z;
    *(float4*)(outX + base + 4) = z;
    return;
  }
  float4 a0 = *(const float4*)(x + base);
  float4 a1 = *(const float4*)(x + base + 4);
  int i = inv[b * (NUSE*SEGF) + s];
  if (i >= 0) {
    size_t hb = (size_t)(b * (NUSE*SEGS) + i) * DIN + lane * 8;
    float4 h0 = *(const float4*)(hm + hb);
    float4 h1 = *(const float4*)(hm + hb + 4);
    a0.x += h0.x; a0.y += h0.y; a0.z += h0.z; a0.w += h0.w;
    a1.x += h1.x; a1.y += h1.y; a1.z += h1.z; a1.w += h1.w;
  }
  *(float4*)(outX + base)     = a0;
  *(float4*)(outX + base + 4) = a1;
}

extern "C" void kernel_launch(void* const* d_in, const int* in_sizes, int n_in,
                              void* d_out, int out_size, void* d_ws, size_t ws_size,
                              hipStream_t stream) {
  (void)in_sizes; (void)n_in; (void)out_size; (void)ws_size;
  const float* x      = (const float*)d_in[0];
  const float* w_samp = (const float*)d_in[1];
  const float* b_samp = (const float*)d_in[2];
  const float* w_q    = (const float*)d_in[3];
  const float* w_k    = (const float*)d_in[4];
  const float* w_v    = (const float*)d_in[5];
  const float* w_o    = (const float*)d_in[6];
  const float* betas  = (const float*)d_in[7];
  const float* w1     = (const float*)d_in[8];
  const float* b1     = (const float*)d_in[9];
  const float* w2     = (const float*)d_in[10];
  const float* b2     = (const float*)d_in[11];

  float* outX      = (float*)d_out;
  float* outMask   = outX + (size_t)BATCH * S_TOT * DIN;
  float* outScores = outMask + (size_t)BATCH * S_TOT;

  char* ws = (char*)d_ws;
  int*   flat  = (int*)(ws);                          // 64 KB
  int*   inv   = (int*)(ws + 65536);                  // 64 KB
  float* M0    = (float*)(ws + 131072);               // 512 KB
  float* z0    = (float*)(ws + 655360);               // 8 KB
  short* Wtqkv = (short*)(ws + 1048576);              // [1536][512] bf16, 1.5 MB
  short* Wto   = (short*)(ws + 2621440);              // [512][512]
  short* Wt1   = (short*)(ws + 3145728);              // [2048][512], 2 MB
  short* Wt2   = (short*)(ws + 5242880);              // [512][2048], 2 MB
  short* xsel  = (short*)(ws + 7340032);              // [4096][512], 4 MB
  short* qkv   = (short*)(ws + 11534336);             // [4096][1536], 12 MB
  short* attb  = (short*)(ws + 24117248);             // [4096][512], 4 MB
  short* R0b   = (short*)(ws + 28311552);             // [4096][512], 4 MB
  short* hidB  = (short*)(ws + 7340032);              // [4096][2048] overlays xsel+qkv (dead)
  float* Hf    = (float*)(ws + 32505856);             // [4096][512] fp32, 8 MB

  scores_kernel<<<(BATCH*S_TOT)/4, 256, 0, stream>>>(x, w_samp, b_samp, outScores);
  topk_kernel<<<BATCH*NSEG, 256, 0, stream>>>(outScores, flat, inv, outMask);

  transpose_cast<<<dim3(16,16), 256, 0, stream>>>(w_q, Wtqkv, 512, 512, 0);
  transpose_cast<<<dim3(16,16), 256, 0, stream>>>(w_k, Wtqkv, 512, 512, 512);
  transpose_cast<<<dim3(16,16), 256, 0, stream>>>(w_v, Wtqkv, 512, 512, 1024);
  transpose_cast<<<dim3(16,16), 256, 0, stream>>>(w_o, Wto, 512, 512, 0);
  transpose_cast<<<dim3(64,16), 256, 0, stream>>>(w1, Wt1, 512, 2048, 0);
  transpose_cast<<<dim3(16,64), 256, 0, stream>>>(w2, Wt2, 2048, 512, 0);

  gather_cast<<<MROWS/4, 256, 0, stream>>>(x, flat, xsel);

  // QKV: [4096][512] @ [512][1536] -> qkv bf16
  gemm_bf16<128,128,64,64><<<dim3(12,32), 256, 0, stream>>>(
      xsel, Wtqkv, nullptr, nullptr, qkv, MROWS, 1536, 512, 0);

  memsum_b<<<BATCH*NH, 256, 0, stream>>>(qkv, M0, z0);
  attn2<<<BATCH*NH*NUSE*8, 128, 0, stream>>>(qkv, M0, z0, betas, attb);

  // out-proj: att @ w_o -> R0b bf16
  gemm_bf16<64,128,64,32><<<dim3(4,64), 256, 0, stream>>>(
      attb, Wto, nullptr, nullptr, R0b, MROWS, 512, 512, 0);
  // MLP1: gelu(R0 @ w1 + b1) -> hidB bf16
  gemm_bf16<128,128,64,64><<<dim3(16,32), 256, 0, stream>>>(
      R0b, Wt1, b1, nullptr, hidB, MROWS, 2048, 512, 1);
  // MLP2: hid @ w2 + b2 -> Hf fp32
  gemm_bf16<64,128,64,32><<<dim3(4,64), 256, 0, stream>>>(
      hidB, Wt2, b2, Hf, nullptr, MROWS, 512, 2048, 0);

  final_kernel<<<(BATCH*S_TOT)/4, 256, 0, stream>>>(x, inv, Hf, outX);
}

// Round 3
// 560.784 us; speedup vs baseline: 3.5543x; 2.1303x over previous
//
#include <hip/hip_runtime.h>
#include <math.h>

#define S_TOT 16384
#define BATCH 4
#define DIN 512
#define NH 8
#define DK 64
#define SEGF 2048
#define SEGS 512
#define NSEG 8
#define NUSE 2
#define MROWS (BATCH*NUSE*SEGS)   // 4096 rows through attention/MLP

typedef unsigned int u32;
typedef __attribute__((ext_vector_type(8))) short short8;
typedef __attribute__((ext_vector_type(4))) float f32x4;

__device__ __forceinline__ short f2b(float f) {
  u32 u = __float_as_uint(f);
  u32 r = u + 0x7fffu + ((u >> 16) & 1u);
  return (short)(r >> 16);
}
__device__ __forceinline__ float b2f_lo(u32 u) { return __uint_as_float(u << 16); }
__device__ __forceinline__ float b2f_hi(u32 u) { return __uint_as_float(u & 0xffff0000u); }

// ---------------- scores = x @ w_samp + b (fp32, exact for routing) ----------------
__global__ __launch_bounds__(256) void scores_kernel(
    const float* __restrict__ x, const float* __restrict__ w,
    const float* __restrict__ bsamp, float* __restrict__ out)
{
  int tok  = blockIdx.x * 4 + (threadIdx.x >> 6);
  int lane = threadIdx.x & 63;
  const float* xr = x + (size_t)tok * DIN;
  float p = 0.f;
  #pragma unroll
  for (int it = 0; it < 8; ++it)
    p += xr[lane + it*64] * w[lane + it*64];
  #pragma unroll
  for (int off = 32; off > 0; off >>= 1) p += __shfl_down(p, off);
  if (lane == 0) out[tok] = p + bsamp[0];
}

// ---------------- topk pass 1: stable rank of every element, all CUs ----------------
// grid = 256 blocks: c = chunk(8) | g = seg(8) | b = batch(4); 256 threads, 1 elem each
__global__ __launch_bounds__(256) void topk_rank(
    const float* __restrict__ scores, int* __restrict__ flags,
    float* __restrict__ maskOut)
{
  int c = blockIdx.x & 7, g = (blockIdx.x >> 3) & 7, b = blockIdx.x >> 6;
  __shared__ float sc[SEGF];
  int tid = threadIdx.x;
  const float* src = scores + (size_t)b*S_TOT + (size_t)g*SEGF;
  *(float4*)&sc[tid*8]     = *(const float4*)(src + tid*8);
  *(float4*)&sc[tid*8 + 4] = *(const float4*)(src + tid*8 + 4);
  __syncthreads();
  int i0 = c*256 + tid;
  float mine = sc[i0];
  int cnt = 0;
  #pragma unroll 2
  for (int j = 0; j < SEGF; j += 8) {
    float4 a = *(const float4*)&sc[j];
    float4 d = *(const float4*)&sc[j + 4];
    cnt += (a.x > mine || (a.x == mine && (j+0) < i0)) ? 1 : 0;
    cnt += (a.y > mine || (a.y == mine && (j+1) < i0)) ? 1 : 0;
    cnt += (a.z > mine || (a.z == mine && (j+2) < i0)) ? 1 : 0;
    cnt += (a.w > mine || (a.w == mine && (j+3) < i0)) ? 1 : 0;
    cnt += (d.x > mine || (d.x == mine && (j+4) < i0)) ? 1 : 0;
    cnt += (d.y > mine || (d.y == mine && (j+5) < i0)) ? 1 : 0;
    cnt += (d.z > mine || (d.z == mine && (j+6) < i0)) ? 1 : 0;
    cnt += (d.w > mine || (d.w == mine && (j+7) < i0)) ? 1 : 0;
  }
  int flg = (cnt < SEGS) ? 1 : 0;
  flags[(((b << 3) + g) << 11) + i0] = flg;
  maskOut[(size_t)b*S_TOT + (size_t)g*SEGF + i0] = flg ? 1.0f : 0.0f;
}

// ---------------- topk pass 2: compact selected indices (only g<NUSE needed) ------
// grid = BATCH*NUSE blocks, 256 threads, 8 elems each
__global__ __launch_bounds__(256) void topk_compact(
    const int* __restrict__ flags, int* __restrict__ flat, int* __restrict__ inv)
{
  int g = blockIdx.x & 1, b = blockIdx.x >> 1;
  __shared__ int wsum[4];
  int tid = threadIdx.x;
  int lane = tid & 63, w = tid >> 6;
  const int* f = flags + (((b << 3) + g) << 11);
  int fl[8]; int ls = 0;
  #pragma unroll
  for (int l = 0; l < 8; ++l) { fl[l] = f[tid*8 + l]; ls += fl[l]; }
  int inc = ls;
  #pragma unroll
  for (int off = 1; off < 64; off <<= 1) {
    int t = __shfl_up(inc, off);
    if (lane >= off) inc += t;
  }
  if (lane == 63) wsum[w] = inc;
  __syncthreads();
  int base = 0;
  #pragma unroll
  for (int ww = 0; ww < 4; ++ww) base += (ww < w) ? wsum[ww] : 0;
  int pos = base + inc - ls;
  #pragma unroll
  for (int l = 0; l < 8; ++l) {
    int i = tid*8 + l;
    inv[b*(NUSE*SEGF) + g*SEGF + i] = fl[l] ? (g*SEGS + pos) : -1;
    if (fl[l]) {
      flat[b*(NSEG*SEGS) + g*SEGS + pos] = g*SEGF + i;
      pos++;
    }
  }
}

// ---------------- transpose+cast weights: src[K][N] fp32 -> dst[(rowoff+n)][k] bf16
__global__ __launch_bounds__(256) void transpose_cast(
    const float* __restrict__ src, short* __restrict__ dst,
    int K, int N, int rowoff)
{
  __shared__ float t[32][33];
  int tid = threadIdx.x;
  int txx = tid & 31, ty = tid >> 5;
  int n0 = blockIdx.x * 32, k0 = blockIdx.y * 32;
  #pragma unroll
  for (int r = 0; r < 4; ++r)
    t[ty + 8*r][txx] = src[(size_t)(k0 + ty + 8*r) * N + n0 + txx];
  __syncthreads();
  #pragma unroll
  for (int r = 0; r < 4; ++r)
    dst[(size_t)(rowoff + n0 + ty + 8*r) * K + k0 + txx] = f2b(t[txx][ty + 8*r]);
}

// ---------------- gather selected rows of x, cast to bf16 ----------------
__global__ __launch_bounds__(256) void gather_cast(
    const float* __restrict__ x, const int* __restrict__ flat,
    short* __restrict__ xsel)
{
  int tok  = blockIdx.x * 4 + (threadIdx.x >> 6);
  int lane = threadIdx.x & 63;
  int b = tok >> 10, i = tok & 1023;
  int gidx = flat[b * (NSEG*SEGS) + i];
  const float* srcp = x + ((size_t)(b * S_TOT + gidx)) * DIN + lane*8;
  float4 a0 = *(const float4*)srcp;
  float4 a1 = *(const float4*)(srcp + 4);
  uint4 o;
  o.x = (u32)(unsigned short)f2b(a0.x) | ((u32)(unsigned short)f2b(a0.y) << 16);
  o.y = (u32)(unsigned short)f2b(a0.z) | ((u32)(unsigned short)f2b(a0.w) << 16);
  o.z = (u32)(unsigned short)f2b(a1.x) | ((u32)(unsigned short)f2b(a1.y) << 16);
  o.w = (u32)(unsigned short)f2b(a1.z) | ((u32)(unsigned short)f2b(a1.w) << 16);
  *(uint4*)(xsel + (size_t)tok * DIN + lane*8) = o;
}

// ---------------- bf16 MFMA GEMM: C[M][N] = act(A[M][K] @ Bt[N][K]^T + bias) -------
template<int BM, int BN, int WM, int WN>
__global__ __launch_bounds__(256) void gemm_bf16(
    const short* __restrict__ A, const short* __restrict__ Bt,
    const float* __restrict__ bias, float* __restrict__ Cf,
    short* __restrict__ Cb, int M, int N, int K, int act)
{
  constexpr int BK = 32;
  constexpr int WAVES_N = BN / WN;
  constexpr int FM = WM / 16, FN = WN / 16;
  __shared__ short Al[BM * BK];
  __shared__ short Bl[BN * BK];
  const int tid = threadIdx.x;
  const int lane = tid & 63, wid = tid >> 6;
  const int wr = wid / WAVES_N, wc = wid % WAVES_N;
  const int bm = blockIdx.y * BM, bn = blockIdx.x * BN;
  const int srow = tid >> 2;
  const int scol = (tid & 3) * 8;

  f32x4 acc[FM][FN];
  #pragma unroll
  for (int i = 0; i < FM; ++i)
    #pragma unroll
    for (int j = 0; j < FN; ++j)
      #pragma unroll
      for (int e = 0; e < 4; ++e) acc[i][j][e] = 0.f;

  for (int k0 = 0; k0 < K; k0 += BK) {
    __syncthreads();
    #pragma unroll
    for (int i = 0; i < BM/64; ++i) {
      const short* gp = A + (size_t)(bm + i*64 + srow) * K + k0 + scol;
      __builtin_amdgcn_global_load_lds(
          (const __attribute__((address_space(1))) void*)gp,
          (__attribute__((address_space(3))) void*)&Al[(i*64 + srow)*BK + scol],
          16, 0, 0);
    }
    #pragma unroll
    for (int i = 0; i < BN/64; ++i) {
      const short* gp = Bt + (size_t)(bn + i*64 + srow) * K + k0 + scol;
      __builtin_amdgcn_global_load_lds(
          (const __attribute__((address_space(1))) void*)gp,
          (__attribute__((address_space(3))) void*)&Bl[(i*64 + srow)*BK + scol],
          16, 0, 0);
    }
    __syncthreads();
    short8 af[FM], bf_[FN];
    #pragma unroll
    for (int fm = 0; fm < FM; ++fm)
      af[fm] = *(const short8*)&Al[(wr*WM + fm*16 + (lane & 15))*BK + (lane >> 4)*8];
    #pragma unroll
    for (int fn = 0; fn < FN; ++fn)
      bf_[fn] = *(const short8*)&Bl[(wc*WN + fn*16 + (lane & 15))*BK + (lane >> 4)*8];
    #pragma unroll
    for (int fm = 0; fm < FM; ++fm)
      #pragma unroll
      for (int fn = 0; fn < FN; ++fn)
        acc[fm][fn] = __builtin_amdgcn_mfma_f32_16x16x32_bf16(af[fm], bf_[fn], acc[fm][fn], 0, 0, 0);
  }

  const int crow0 = (lane >> 4) * 4, ccol = lane & 15;
  #pragma unroll
  for (int fm = 0; fm < FM; ++fm) {
    #pragma unroll
    for (int fn = 0; fn < FN; ++fn) {
      #pragma unroll
      for (int j = 0; j < 4; ++j) {
        int r = bm + wr*WM + fm*16 + crow0 + j;
        int c = bn + wc*WN + fn*16 + ccol;
        float v = acc[fm][fn][j];
        if (bias) v += bias[c];
        if (act == 1) v = 0.5f * v * (1.0f + erff(v * 0.70710678118f));
        if (Cf) Cf[(size_t)r * N + c] = v;
        if (Cb) Cb[(size_t)r * N + c] = f2b(v);
      }
    }
  }
}

// ---------------- M0 = (elu(k)+1)^T @ v over seg0, z0 = sum ----------------
__global__ __launch_bounds__(256) void memsum_b(
    const short* __restrict__ qkv, float* __restrict__ M0, float* __restrict__ z0)
{
  int b = blockIdx.x >> 3, h = blockIdx.x & 7;
  __shared__ float Ks[64][64];
  __shared__ float Vs[64][64];
  int tid = threadIdx.x;
  int tx = tid & 15, ty = tid >> 4;
  int d4 = (tid & 15) * 4, sl = tid >> 4;
  float acc[4][4] = {};
  float zacc[4] = {0.f,0.f,0.f,0.f};
  for (int c = 0; c < 8; ++c) {
    #pragma unroll
    for (int l = 0; l < 4; ++l) {
      int r = c*64 + sl + l*16;
      size_t grow = (size_t)(b*1024 + r) * 1536 + h*64 + d4;
      uint2 kk = *(const uint2*)(qkv + grow + 512);
      float f0 = b2f_lo(kk.x), f1 = b2f_hi(kk.x), f2v = b2f_lo(kk.y), f3 = b2f_hi(kk.y);
      Ks[sl + l*16][d4+0] = f0 > 0.f ? f0 + 1.f : __expf(f0);
      Ks[sl + l*16][d4+1] = f1 > 0.f ? f1 + 1.f : __expf(f1);
      Ks[sl + l*16][d4+2] = f2v > 0.f ? f2v + 1.f : __expf(f2v);
      Ks[sl + l*16][d4+3] = f3 > 0.f ? f3 + 1.f : __expf(f3);
      uint2 vv = *(const uint2*)(qkv + grow + 1024);
      Vs[sl + l*16][d4+0] = b2f_lo(vv.x);
      Vs[sl + l*16][d4+1] = b2f_hi(vv.x);
      Vs[sl + l*16][d4+2] = b2f_lo(vv.y);
      Vs[sl + l*16][d4+3] = b2f_hi(vv.y);
    }
    __syncthreads();
    for (int s2 = 0; s2 < 64; ++s2) {
      float4 a  = *(const float4*)&Ks[s2][ty*4];
      float4 bb = *(const float4*)&Vs[s2][tx*4];
      acc[0][0] += a.x*bb.x; acc[0][1] += a.x*bb.y; acc[0][2] += a.x*bb.z; acc[0][3] += a.x*bb.w;
      acc[1][0] += a.y*bb.x; acc[1][1] += a.y*bb.y; acc[1][2] += a.y*bb.z; acc[1][3] += a.y*bb.w;
      acc[2][0] += a.z*bb.x; acc[2][1] += a.z*bb.y; acc[2][2] += a.z*bb.z; acc[2][3] += a.z*bb.w;
      acc[3][0] += a.w*bb.x; acc[3][1] += a.w*bb.y; acc[3][2] += a.w*bb.z; acc[3][3] += a.w*bb.w;
      if (tx == 0) { zacc[0]+=a.x; zacc[1]+=a.y; zacc[2]+=a.z; zacc[3]+=a.w; }
    }
    __syncthreads();
  }
  size_t mb = (size_t)(b*NH + h) * 4096;
  #pragma unroll
  for (int i = 0; i < 4; ++i)
    #pragma unroll
    for (int j = 0; j < 4; ++j)
      M0[mb + (size_t)(ty*4 + i)*64 + tx*4 + j] = acc[i][j];
  if (tx == 0) {
    #pragma unroll
    for (int i = 0; i < 4; ++i) z0[(b*NH + h)*64 + ty*4 + i] = zacc[i];
  }
}

// ---------------- attention: 512 blocks x 128 threads ----------------
__global__ __launch_bounds__(128) void attn2(
    const short* __restrict__ qkv, const float* __restrict__ M0g,
    const float* __restrict__ z0g, const float* __restrict__ betas,
    short* __restrict__ att)
{
  __shared__ char smem[50944];
  int tid = threadIdx.x;
  int lane = tid & 63, kw = tid >> 6;
  int bx = blockIdx.x;
  int qc = bx & 7, g = (bx >> 3) & 1, h = (bx >> 4) & 7, b = bx >> 7;
  int qrow = b*1024 + g*512 + qc*64 + lane;

  float qv[64];
  {
    const u32* qp = (const u32*)(qkv + (size_t)qrow*1536 + h*64);
    #pragma unroll
    for (int i = 0; i < 32; ++i) {
      u32 u = qp[i];
      qv[2*i]   = b2f_lo(u);
      qv[2*i+1] = b2f_hi(u);
    }
  }

  float* Kc = (float*)(smem + kw*16384);
  float* Vc = (float*)(smem + kw*16384 + 8192);
  float acc[64];
  #pragma unroll
  for (int d = 0; d < 64; ++d) acc[d] = 0.f;
  float lsum = 0.f;

  const size_t kvrow0 = (size_t)(b*1024 + g*512);
  for (int c = 0; c < 8; ++c) {
    int kbase = kw*256 + c*32;
    #pragma unroll
    for (int i = 0; i < 8; ++i) {
      int j  = i*4 + (lane >> 4);
      int d0 = (lane & 15) * 4;
      size_t grow = (kvrow0 + kbase + j) * 1536 + h*64 + d0;
      uint2 kk = *(const uint2*)(qkv + grow + 512);
      int e = i*256 + lane*4;
      Kc[e+0] = b2f_lo(kk.x); Kc[e+1] = b2f_hi(kk.x);
      Kc[e+2] = b2f_lo(kk.y); Kc[e+3] = b2f_hi(kk.y);
      uint2 vv = *(const uint2*)(qkv + grow + 1024);
      Vc[e+0] = b2f_lo(vv.x); Vc[e+1] = b2f_hi(vv.x);
      Vc[e+2] = b2f_lo(vv.y); Vc[e+3] = b2f_hi(vv.y);
    }
    for (int j = 0; j < 32; ++j) {
      const float* kr = &Kc[j*64];
      float s = 0.f;
      #pragma unroll
      for (int d = 0; d < 64; ++d) s = fmaf(qv[d], kr[d], s);
      float p = __expf(s * 0.125f);
      lsum += p;
      const float* vr = &Vc[j*64];
      #pragma unroll
      for (int d = 0; d < 64; ++d) acc[d] = fmaf(p, vr[d], acc[d]);
    }
  }

  float* exch = (float*)(smem + 32768);
  {
    float* exW = exch + (kw*64 + lane)*35;
    int oh = kw ^ 1;
    #pragma unroll
    for (int d = 0; d < 32; ++d) exW[d] = acc[oh*32 + d];
    exW[32] = lsum;
  }
  __syncthreads();
  float* M0l = (float*)smem;
  float* zb  = (float*)(smem + 50688);
  if (g) {
    const float* src = M0g + (size_t)(b*NH + h) * 4096;
    for (int i = tid; i < 1024; i += 128)
      *(float4*)&M0l[i*4] = *(const float4*)&src[i*4];
    if (tid < 64) zb[tid] = 0.015625f + z0g[(b*NH + h)*64 + tid];
  }
  __syncthreads();

  float acch[32]; float l2;
  {
    const float* exR = exch + ((kw^1)*64 + lane)*35;
    l2 = exR[32];
    #pragma unroll
    for (int d = 0; d < 32; ++d) acch[d] = acc[kw*32 + d] + exR[d];
  }
  float linv = 1.f / (lsum + l2);

  float sq[64];
  #pragma unroll
  for (int d = 0; d < 64; ++d) {
    float qd = qv[d];
    sq[d] = qd > 0.f ? qd + 1.f : __expf(qd);
  }

  float num[32];
  #pragma unroll
  for (int dd = 0; dd < 32; ++dd) num[dd] = 0.f;
  if (g) {
    float den = 0.f;
    for (int d = 0; d < 64; ++d) {
      float s = sq[d];
      den = fmaf(s, zb[d], den);
      const float* mr = &M0l[d*64 + kw*32];
      #pragma unroll
      for (int dd = 0; dd < 32; ++dd) num[dd] = fmaf(s, mr[dd], num[dd]);
    }
    float dinv = 1.f / den;
    #pragma unroll
    for (int dd = 0; dd < 32; ++dd) num[dd] *= dinv;
  }

  u32 ow[16];
  #pragma unroll
  for (int dd = 0; dd < 32; dd += 2) {
    float bt0 = betas[h*64 + kw*32 + dd];
    float bt1 = betas[h*64 + kw*32 + dd + 1];
    float g0 = 1.f / (1.f + __expf(-bt0));
    float g1 = 1.f / (1.f + __expf(-bt1));
    float v0 = g0 * num[dd]   + (1.f - g0) * acch[dd]   * linv;
    float v1 = g1 * num[dd+1] + (1.f - g1) * acch[dd+1] * linv;
    ow[dd>>1] = (u32)(unsigned short)f2b(v0) | ((u32)(unsigned short)f2b(v1) << 16);
  }
  u32* op = (u32*)(att + (size_t)qrow*512 + h*64 + kw*32);
  #pragma unroll
  for (int i = 0; i < 4; ++i)
    *(uint4*)(op + i*4) = make_uint4(ow[i*4], ow[i*4+1], ow[i*4+2], ow[i*4+3]);
}

// ---------------- final: x_out = (x + scatter(h)) * pad ----------------
__global__ __launch_bounds__(256) void final_kernel(
    const float* __restrict__ x, const int* __restrict__ inv,
    const float* __restrict__ hm, float* __restrict__ outX)
{
  int row  = blockIdx.x * 4 + (threadIdx.x >> 6);
  int lane = threadIdx.x & 63;
  int b = row >> 14;
  int s = row & (S_TOT - 1);
  size_t base = (size_t)row * DIN + lane * 8;
  if (s >= NUSE * SEGF) {
    float4 z = make_float4(0.f,0.f,0.f,0.f);
    *(float4*)(outX + base)     = z;
    *(float4*)(outX + base + 4) = z;
    return;
  }
  float4 a0 = *(const float4*)(x + base);
  float4 a1 = *(const float4*)(x + base + 4);
  int i = inv[b * (NUSE*SEGF) + s];
  if (i >= 0) {
    size_t hb = (size_t)(b * (NUSE*SEGS) + i) * DIN + lane * 8;
    float4 h0 = *(const float4*)(hm + hb);
    float4 h1 = *(const float4*)(hm + hb + 4);
    a0.x += h0.x; a0.y += h0.y; a0.z += h0.z; a0.w += h0.w;
    a1.x += h1.x; a1.y += h1.y; a1.z += h1.z; a1.w += h1.w;
  }
  *(float4*)(outX + base)     = a0;
  *(float4*)(outX + base + 4) = a1;
}

extern "C" void kernel_launch(void* const* d_in, const int* in_sizes, int n_in,
                              void* d_out, int out_size, void* d_ws, size_t ws_size,
                              hipStream_t stream) {
  (void)in_sizes; (void)n_in; (void)out_size; (void)ws_size;
  const float* x      = (const float*)d_in[0];
  const float* w_samp = (const float*)d_in[1];
  const float* b_samp = (const float*)d_in[2];
  const float* w_q    = (const float*)d_in[3];
  const float* w_k    = (const float*)d_in[4];
  const float* w_v    = (const float*)d_in[5];
  const float* w_o    = (const float*)d_in[6];
  const float* betas  = (const float*)d_in[7];
  const float* w1     = (const float*)d_in[8];
  const float* b1     = (const float*)d_in[9];
  const float* w2     = (const float*)d_in[10];
  const float* b2     = (const float*)d_in[11];

  float* outX      = (float*)d_out;
  float* outMask   = outX + (size_t)BATCH * S_TOT * DIN;
  float* outScores = outMask + (size_t)BATCH * S_TOT;

  char* ws = (char*)d_ws;
  int*   flat  = (int*)(ws);                          // 64 KB
  int*   inv   = (int*)(ws + 65536);                  // 64 KB
  float* M0    = (float*)(ws + 131072);               // 512 KB
  float* z0    = (float*)(ws + 655360);               // 8 KB
  int*   flags = (int*)(ws + 720896);                 // [4][8][2048] int, 256 KB
  short* Wtqkv = (short*)(ws + 1048576);              // [1536][512] bf16, 1.5 MB
  short* Wto   = (short*)(ws + 2621440);              // [512][512]
  short* Wt1   = (short*)(ws + 3145728);              // [2048][512], 2 MB
  short* Wt2   = (short*)(ws + 5242880);              // [512][2048], 2 MB
  short* xsel  = (short*)(ws + 7340032);              // [4096][512], 4 MB
  short* qkv   = (short*)(ws + 11534336);             // [4096][1536], 12 MB
  short* attb  = (short*)(ws + 24117248);             // [4096][512], 4 MB
  short* R0b   = (short*)(ws + 28311552);             // [4096][512], 4 MB
  short* hidB  = (short*)(ws + 7340032);              // [4096][2048] overlays xsel+qkv
  float* Hf    = (float*)(ws + 32505856);             // [4096][512] fp32, 8 MB

  scores_kernel<<<(BATCH*S_TOT)/4, 256, 0, stream>>>(x, w_samp, b_samp, outScores);
  topk_rank<<<BATCH*NSEG*8, 256, 0, stream>>>(outScores, flags, outMask);
  topk_compact<<<BATCH*NUSE, 256, 0, stream>>>(flags, flat, inv);

  transpose_cast<<<dim3(16,16), 256, 0, stream>>>(w_q, Wtqkv, 512, 512, 0);
  transpose_cast<<<dim3(16,16), 256, 0, stream>>>(w_k, Wtqkv, 512, 512, 512);
  transpose_cast<<<dim3(16,16), 256, 0, stream>>>(w_v, Wtqkv, 512, 512, 1024);
  transpose_cast<<<dim3(16,16), 256, 0, stream>>>(w_o, Wto, 512, 512, 0);
  transpose_cast<<<dim3(64,16), 256, 0, stream>>>(w1, Wt1, 512, 2048, 0);
  transpose_cast<<<dim3(16,64), 256, 0, stream>>>(w2, Wt2, 2048, 512, 0);

  gather_cast<<<MROWS/4, 256, 0, stream>>>(x, flat, xsel);

  gemm_bf16<128,128,64,64><<<dim3(12,32), 256, 0, stream>>>(
      xsel, Wtqkv, nullptr, nullptr, qkv, MROWS, 1536, 512, 0);

  memsum_b<<<BATCH*NH, 256, 0, stream>>>(qkv, M0, z0);
  attn2<<<BATCH*NH*NUSE*8, 128, 0, stream>>>(qkv, M0, z0, betas, attb);

  gemm_bf16<64,128,64,32><<<dim3(4,64), 256, 0, stream>>>(
      attb, Wto, nullptr, nullptr, R0b, MROWS, 512, 512, 0);
  gemm_bf16<128,128,64,64><<<dim3(16,32), 256, 0, stream>>>(
      R0b, Wt1, b1, nullptr, hidB, MROWS, 2048, 512, 1);
  gemm_bf16<64,128,64,32><<<dim3(4,64), 256, 0, stream>>>(
      hidB, Wt2, b2, Hf, nullptr, MROWS, 512, 2048, 0);

  final_kernel<<<(BATCH*S_TOT)/4, 256, 0, stream>>>(x, inv, Hf, outX);
}

// Round 4
// 306.897 us; speedup vs baseline: 6.4947x; 1.8273x over previous
//
#include <hip/hip_runtime.h>
#include <math.h>

#define S_TOT 16384
#define BATCH 4
#define DIN 512
#define NH 8
#define DK 64
#define SEGF 2048
#define SEGS 512
#define NSEG 8
#define NUSE 2
#define MROWS (BATCH*NUSE*SEGS)   // 4096 rows through attention/MLP

typedef unsigned int u32;
typedef __attribute__((ext_vector_type(8))) short short8;
typedef __attribute__((ext_vector_type(4))) float f32x4;

__device__ __forceinline__ short f2b(float f) {
  u32 u = __float_as_uint(f);
  u32 r = u + 0x7fffu + ((u >> 16) & 1u);
  return (short)(r >> 16);
}
__device__ __forceinline__ float b2f(short s) {
  return __uint_as_float(((u32)(unsigned short)s) << 16);
}
__device__ __forceinline__ float b2f_lo(u32 u) { return __uint_as_float(u << 16); }
__device__ __forceinline__ float b2f_hi(u32 u) { return __uint_as_float(u & 0xffff0000u); }

// ---------------- scores = x @ w_samp + b (fp32, exact for routing) ----------------
__global__ __launch_bounds__(256) void scores_kernel(
    const float* __restrict__ x, const float* __restrict__ w,
    const float* __restrict__ bsamp, float* __restrict__ out)
{
  int tok  = blockIdx.x * 4 + (threadIdx.x >> 6);
  int lane = threadIdx.x & 63;
  const float* xr = x + (size_t)tok * DIN;
  float p = 0.f;
  #pragma unroll
  for (int it = 0; it < 8; ++it)
    p += xr[lane + it*64] * w[lane + it*64];
  #pragma unroll
  for (int off = 32; off > 0; off >>= 1) p += __shfl_down(p, off);
  if (lane == 0) out[tok] = p + bsamp[0];
}

// ---------------- topk pass 1: stable rank of every element ----------------
__global__ __launch_bounds__(256) void topk_rank(
    const float* __restrict__ scores, int* __restrict__ flags,
    float* __restrict__ maskOut)
{
  int c = blockIdx.x & 7, g = (blockIdx.x >> 3) & 7, b = blockIdx.x >> 6;
  __shared__ float sc[SEGF];
  int tid = threadIdx.x;
  const float* src = scores + (size_t)b*S_TOT + (size_t)g*SEGF;
  *(float4*)&sc[tid*8]     = *(const float4*)(src + tid*8);
  *(float4*)&sc[tid*8 + 4] = *(const float4*)(src + tid*8 + 4);
  __syncthreads();
  int i0 = c*256 + tid;
  float mine = sc[i0];
  int cnt = 0;
  #pragma unroll 2
  for (int j = 0; j < SEGF; j += 8) {
    float4 a = *(const float4*)&sc[j];
    float4 d = *(const float4*)&sc[j + 4];
    cnt += (a.x > mine || (a.x == mine && (j+0) < i0)) ? 1 : 0;
    cnt += (a.y > mine || (a.y == mine && (j+1) < i0)) ? 1 : 0;
    cnt += (a.z > mine || (a.z == mine && (j+2) < i0)) ? 1 : 0;
    cnt += (a.w > mine || (a.w == mine && (j+3) < i0)) ? 1 : 0;
    cnt += (d.x > mine || (d.x == mine && (j+4) < i0)) ? 1 : 0;
    cnt += (d.y > mine || (d.y == mine && (j+5) < i0)) ? 1 : 0;
    cnt += (d.z > mine || (d.z == mine && (j+6) < i0)) ? 1 : 0;
    cnt += (d.w > mine || (d.w == mine && (j+7) < i0)) ? 1 : 0;
  }
  int flg = (cnt < SEGS) ? 1 : 0;
  flags[(((b << 3) + g) << 11) + i0] = flg;
  maskOut[(size_t)b*S_TOT + (size_t)g*SEGF + i0] = flg ? 1.0f : 0.0f;
}

// ---------------- topk pass 2: compact selected indices (g<NUSE) ----------------
__global__ __launch_bounds__(256) void topk_compact(
    const int* __restrict__ flags, int* __restrict__ flat, int* __restrict__ inv)
{
  int g = blockIdx.x & 1, b = blockIdx.x >> 1;
  __shared__ int wsum[4];
  int tid = threadIdx.x;
  int lane = tid & 63, w = tid >> 6;
  const int* f = flags + (((b << 3) + g) << 11);
  int fl[8]; int ls = 0;
  #pragma unroll
  for (int l = 0; l < 8; ++l) { fl[l] = f[tid*8 + l]; ls += fl[l]; }
  int inc = ls;
  #pragma unroll
  for (int off = 1; off < 64; off <<= 1) {
    int t = __shfl_up(inc, off);
    if (lane >= off) inc += t;
  }
  if (lane == 63) wsum[w] = inc;
  __syncthreads();
  int base = 0;
  #pragma unroll
  for (int ww = 0; ww < 4; ++ww) base += (ww < w) ? wsum[ww] : 0;
  int pos = base + inc - ls;
  #pragma unroll
  for (int l = 0; l < 8; ++l) {
    int i = tid*8 + l;
    inv[b*(NUSE*SEGF) + g*SEGF + i] = fl[l] ? (g*SEGS + pos) : -1;
    if (fl[l]) {
      flat[b*(NSEG*SEGS) + g*SEGS + pos] = g*SEGF + i;
      pos++;
    }
  }
}

// ---------------- transpose+cast weights: src[K][N] fp32 -> dst[(rowoff+n)][k] bf16
__global__ __launch_bounds__(256) void transpose_cast(
    const float* __restrict__ src, short* __restrict__ dst,
    int K, int N, int rowoff)
{
  __shared__ float t[32][33];
  int tid = threadIdx.x;
  int txx = tid & 31, ty = tid >> 5;
  int n0 = blockIdx.x * 32, k0 = blockIdx.y * 32;
  #pragma unroll
  for (int r = 0; r < 4; ++r)
    t[ty + 8*r][txx] = src[(size_t)(k0 + ty + 8*r) * N + n0 + txx];
  __syncthreads();
  #pragma unroll
  for (int r = 0; r < 4; ++r)
    dst[(size_t)(rowoff + n0 + ty + 8*r) * K + k0 + txx] = f2b(t[txx][ty + 8*r]);
}

// ---------------- gather selected rows of x, cast to bf16 ----------------
__global__ __launch_bounds__(256) void gather_cast(
    const float* __restrict__ x, const int* __restrict__ flat,
    short* __restrict__ xsel)
{
  int tok  = blockIdx.x * 4 + (threadIdx.x >> 6);
  int lane = threadIdx.x & 63;
  int b = tok >> 10, i = tok & 1023;
  int gidx = flat[b * (NSEG*SEGS) + i];
  const float* srcp = x + ((size_t)(b * S_TOT + gidx)) * DIN + lane*8;
  float4 a0 = *(const float4*)srcp;
  float4 a1 = *(const float4*)(srcp + 4);
  uint4 o;
  o.x = (u32)(unsigned short)f2b(a0.x) | ((u32)(unsigned short)f2b(a0.y) << 16);
  o.y = (u32)(unsigned short)f2b(a0.z) | ((u32)(unsigned short)f2b(a0.w) << 16);
  o.z = (u32)(unsigned short)f2b(a1.x) | ((u32)(unsigned short)f2b(a1.y) << 16);
  o.w = (u32)(unsigned short)f2b(a1.z) | ((u32)(unsigned short)f2b(a1.w) << 16);
  *(uint4*)(xsel + (size_t)tok * DIN + lane*8) = o;
}

// ---------------- bf16 MFMA GEMM: C[M][N] = act(A[M][K] @ Bt[N][K]^T + bias) -------
// VtOut: optional transposed copy of cols >=1024 (the V block): Vt[b][h][dv][key]
template<int BM, int BN, int WM, int WN>
__global__ __launch_bounds__(256) void gemm_bf16(
    const short* __restrict__ A, const short* __restrict__ Bt,
    const float* __restrict__ bias, float* __restrict__ Cf,
    short* __restrict__ Cb, short* __restrict__ VtOut,
    int M, int N, int K, int act)
{
  constexpr int BK = 32;
  constexpr int WAVES_N = BN / WN;
  constexpr int FM = WM / 16, FN = WN / 16;
  __shared__ short Al[BM * BK];
  __shared__ short Bl[BN * BK];
  const int tid = threadIdx.x;
  const int lane = tid & 63, wid = tid >> 6;
  const int wr = wid / WAVES_N, wc = wid % WAVES_N;
  const int bm = blockIdx.y * BM, bn = blockIdx.x * BN;
  const int srow = tid >> 2;
  const int scol = (tid & 3) * 8;

  f32x4 acc[FM][FN];
  #pragma unroll
  for (int i = 0; i < FM; ++i)
    #pragma unroll
    for (int j = 0; j < FN; ++j)
      #pragma unroll
      for (int e = 0; e < 4; ++e) acc[i][j][e] = 0.f;

  for (int k0 = 0; k0 < K; k0 += BK) {
    __syncthreads();
    #pragma unroll
    for (int i = 0; i < BM/64; ++i) {
      const short* gp = A + (size_t)(bm + i*64 + srow) * K + k0 + scol;
      __builtin_amdgcn_global_load_lds(
          (const __attribute__((address_space(1))) void*)gp,
          (__attribute__((address_space(3))) void*)&Al[(i*64 + srow)*BK + scol],
          16, 0, 0);
    }
    #pragma unroll
    for (int i = 0; i < BN/64; ++i) {
      const short* gp = Bt + (size_t)(bn + i*64 + srow) * K + k0 + scol;
      __builtin_amdgcn_global_load_lds(
          (const __attribute__((address_space(1))) void*)gp,
          (__attribute__((address_space(3))) void*)&Bl[(i*64 + srow)*BK + scol],
          16, 0, 0);
    }
    __syncthreads();
    short8 af[FM], bf_[FN];
    #pragma unroll
    for (int fm = 0; fm < FM; ++fm)
      af[fm] = *(const short8*)&Al[(wr*WM + fm*16 + (lane & 15))*BK + (lane >> 4)*8];
    #pragma unroll
    for (int fn = 0; fn < FN; ++fn)
      bf_[fn] = *(const short8*)&Bl[(wc*WN + fn*16 + (lane & 15))*BK + (lane >> 4)*8];
    #pragma unroll
    for (int fm = 0; fm < FM; ++fm)
      #pragma unroll
      for (int fn = 0; fn < FN; ++fn)
        acc[fm][fn] = __builtin_amdgcn_mfma_f32_16x16x32_bf16(af[fm], bf_[fn], acc[fm][fn], 0, 0, 0);
  }

  const int crow0 = (lane >> 4) * 4, ccol = lane & 15;
  #pragma unroll
  for (int fm = 0; fm < FM; ++fm) {
    #pragma unroll
    for (int fn = 0; fn < FN; ++fn) {
      int c = bn + wc*WN + fn*16 + ccol;
      int r0 = bm + wr*WM + fm*16 + crow0;
      float vv[4];
      #pragma unroll
      for (int j = 0; j < 4; ++j) {
        float v = acc[fm][fn][j];
        if (bias) v += bias[c];
        if (act == 1) v = 0.5f * v * (1.0f + erff(v * 0.70710678118f));
        vv[j] = v;
        if (Cf) Cf[(size_t)(r0 + j) * N + c] = v;
        if (Cb) Cb[(size_t)(r0 + j) * N + c] = f2b(v);
      }
      if (VtOut && c >= 1024) {
        int hh = (c - 1024) >> 6, dv = c & 63;
        int bb = r0 >> 10, key = r0 & 1023;
        u32 lo = (u32)(unsigned short)f2b(vv[0]) | ((u32)(unsigned short)f2b(vv[1]) << 16);
        u32 hi = (u32)(unsigned short)f2b(vv[2]) | ((u32)(unsigned short)f2b(vv[3]) << 16);
        *(uint2*)&VtOut[((size_t)((bb*8 + hh)*64 + dv) << 10) + key] = make_uint2(lo, hi);
      }
    }
  }
}

// ---------------- memsum: M0t[b][h][80][64] bf16 = [ (sk^T v)^T ; z ; 0 ] ----------
__global__ __launch_bounds__(256) void memsum_t(
    const short* __restrict__ qkv, short* __restrict__ m0t)
{
  int b = blockIdx.x >> 3, h = blockIdx.x & 7;
  __shared__ float Ks[64][64];
  __shared__ float Vs[64][64];
  int tid = threadIdx.x;
  int tx = tid & 15, ty = tid >> 4;
  int d4 = (tid & 15) * 4, sl = tid >> 4;
  float acc[4][4] = {};
  float zacc[4] = {0.f,0.f,0.f,0.f};
  for (int c = 0; c < 8; ++c) {
    #pragma unroll
    for (int l = 0; l < 4; ++l) {
      int r = c*64 + sl + l*16;
      size_t grow = (size_t)(b*1024 + r) * 1536 + h*64 + d4;
      uint2 kk = *(const uint2*)(qkv + grow + 512);
      float f0 = b2f_lo(kk.x), f1 = b2f_hi(kk.x), f2v = b2f_lo(kk.y), f3 = b2f_hi(kk.y);
      Ks[sl + l*16][d4+0] = f0 > 0.f ? f0 + 1.f : __expf(f0);
      Ks[sl + l*16][d4+1] = f1 > 0.f ? f1 + 1.f : __expf(f1);
      Ks[sl + l*16][d4+2] = f2v > 0.f ? f2v + 1.f : __expf(f2v);
      Ks[sl + l*16][d4+3] = f3 > 0.f ? f3 + 1.f : __expf(f3);
      uint2 vv = *(const uint2*)(qkv + grow + 1024);
      Vs[sl + l*16][d4+0] = b2f_lo(vv.x);
      Vs[sl + l*16][d4+1] = b2f_hi(vv.x);
      Vs[sl + l*16][d4+2] = b2f_lo(vv.y);
      Vs[sl + l*16][d4+3] = b2f_hi(vv.y);
    }
    __syncthreads();
    for (int s2 = 0; s2 < 64; ++s2) {
      float4 a  = *(const float4*)&Ks[s2][ty*4];
      float4 bb = *(const float4*)&Vs[s2][tx*4];
      acc[0][0] += a.x*bb.x; acc[0][1] += a.x*bb.y; acc[0][2] += a.x*bb.z; acc[0][3] += a.x*bb.w;
      acc[1][0] += a.y*bb.x; acc[1][1] += a.y*bb.y; acc[1][2] += a.y*bb.z; acc[1][3] += a.y*bb.w;
      acc[2][0] += a.z*bb.x; acc[2][1] += a.z*bb.y; acc[2][2] += a.z*bb.z; acc[2][3] += a.z*bb.w;
      acc[3][0] += a.w*bb.x; acc[3][1] += a.w*bb.y; acc[3][2] += a.w*bb.z; acc[3][3] += a.w*bb.w;
      if (tx == 0) { zacc[0]+=a.x; zacc[1]+=a.y; zacc[2]+=a.z; zacc[3]+=a.w; }
    }
    __syncthreads();
  }
  // write transposed bf16: M0t[dv][dk] = acc[dk'][dv'], row 64 = z, rows 65..79 = 0
  size_t mb = (size_t)(b*NH + h) * (80*64);
  #pragma unroll
  for (int i = 0; i < 4; ++i)
    #pragma unroll
    for (int j = 0; j < 4; ++j)
      m0t[mb + (size_t)(tx*4 + j)*64 + (ty*4 + i)] = f2b(acc[i][j]);
  if (tx == 0) {
    #pragma unroll
    for (int i = 0; i < 4; ++i)
      m0t[mb + 64*64 + (ty*4 + i)] = f2b(0.015625f + zacc[i]);
  }
  for (int i = tid; i < 15*64; i += 256) m0t[mb + 65*64 + i] = 0;
}

// ---------------- fused MFMA attention ----------------
// grid 256 = (qt:4, h:8, g:2, b:4); 256 threads = 4 waves; wave owns 32 q rows.
__global__ __launch_bounds__(256) void attn3(
    const short* __restrict__ qkv, const short* __restrict__ vt,
    const short* __restrict__ m0t, const float* __restrict__ betas,
    short* __restrict__ att)
{
  __shared__ short Ks[64*72];    // [key][dk], pad 8
  __shared__ short Vts[80*72];   // [dv][key]; row 64 = ones, 65..79 = 0
  __shared__ short Ps[128*72];   // [q][key] (wave-private rows); reused for M0t
  int tid = threadIdx.x, lane = tid & 63, w = tid >> 6;
  int ln15 = lane & 15, hi8 = (lane >> 4) * 8;
  int bx = blockIdx.x;
  int qt = bx & 3, h = (bx >> 2) & 7, g = (bx >> 5) & 1, b = bx >> 6;
  const int seg0 = b*1024 + g*512;
  const int qbase = seg0 + qt*128;
  const int q0w = w*32;

  // Q fragments direct from global (L2-resident, once per block)
  short8 qf[2][2];
  #pragma unroll
  for (int mf = 0; mf < 2; ++mf)
    #pragma unroll
    for (int ks = 0; ks < 2; ++ks)
      qf[mf][ks] = *(const short8*)(qkv + (size_t)(qbase + q0w + mf*16 + ln15)*1536 + h*64 + ks*32 + hi8);

  // static Vts rows 64..79 (ones row at 64 cols 0..63, rest zero)
  for (int i = tid; i < 16*36; i += 256) {
    int r = 64 + i/36, c2 = i%36;
    *(u32*)&Vts[r*72 + c2*2] = (r == 64 && c2 < 32) ? 0x3F803F80u : 0u;
  }

  const int i2a = tid*2, i2b = tid*2 + 1;
  const int kra = i2a>>3, offa = (i2a&7)*8;
  const int krb = i2b>>3, offb = (i2b&7)*8;
  const short* kg = qkv + (size_t)(seg0)*1536 + 512 + h*64;
  const short* vg = vt + ((size_t)((b*8+h)*64) << 10) + g*512;

  uint4 kp[2][2], vp[2][2];
  kp[0][0] = *(const uint4*)(kg + (size_t)(kra)*1536 + offa);
  kp[0][1] = *(const uint4*)(kg + (size_t)(krb)*1536 + offb);
  vp[0][0] = *(const uint4*)(vg + ((size_t)kra << 10) + offa);
  vp[0][1] = *(const uint4*)(vg + ((size_t)krb << 10) + offb);

  f32x4 oacc[2][5];
  #pragma unroll
  for (int mf = 0; mf < 2; ++mf)
    #pragma unroll
    for (int nf = 0; nf < 5; ++nf)
      oacc[mf][nf] = (f32x4){0.f,0.f,0.f,0.f};

  #pragma unroll
  for (int c = 0; c < 8; ++c) {
    __syncthreads();   // all waves done reading previous chunk's Ks/Vts
    *(uint4*)&Ks[kra*72 + offa]  = kp[c&1][0];
    *(uint4*)&Ks[krb*72 + offb]  = kp[c&1][1];
    *(uint4*)&Vts[kra*72 + offa] = vp[c&1][0];   // here kra = dv row index
    *(uint4*)&Vts[krb*72 + offb] = vp[c&1][1];
    if (c < 7) {
      kp[(c+1)&1][0] = *(const uint4*)(kg + (size_t)((c+1)*64 + kra)*1536 + offa);
      kp[(c+1)&1][1] = *(const uint4*)(kg + (size_t)((c+1)*64 + krb)*1536 + offb);
      vp[(c+1)&1][0] = *(const uint4*)(vg + (size_t)((c+1)*64) + ((size_t)kra << 10) + offa);
      vp[(c+1)&1][1] = *(const uint4*)(vg + (size_t)((c+1)*64) + ((size_t)krb << 10) + offb);
    }
    __syncthreads();   // staging visible
    // QK^T
    f32x4 sf[2][4];
    #pragma unroll
    for (int mf = 0; mf < 2; ++mf)
      #pragma unroll
      for (int nf = 0; nf < 4; ++nf)
        sf[mf][nf] = (f32x4){0.f,0.f,0.f,0.f};
    #pragma unroll
    for (int ks = 0; ks < 2; ++ks)
      #pragma unroll
      for (int nf = 0; nf < 4; ++nf) {
        short8 bfr = *(const short8*)&Ks[(nf*16 + ln15)*72 + ks*32 + hi8];
        sf[0][nf] = __builtin_amdgcn_mfma_f32_16x16x32_bf16(qf[0][ks], bfr, sf[0][nf], 0, 0, 0);
        sf[1][nf] = __builtin_amdgcn_mfma_f32_16x16x32_bf16(qf[1][ks], bfr, sf[1][nf], 0, 0, 0);
      }
    // P = exp(S/8) -> bf16 LDS (wave-private rows)
    #pragma unroll
    for (int mf = 0; mf < 2; ++mf)
      #pragma unroll
      for (int nf = 0; nf < 4; ++nf)
        #pragma unroll
        for (int j = 0; j < 4; ++j) {
          float p = __expf(sf[mf][nf][j] * 0.125f);
          Ps[(q0w + mf*16 + (lane>>4)*4 + j)*72 + nf*16 + ln15] = f2b(p);
        }
    // PV (+ ones column -> row-sum l in frag 4)
    #pragma unroll
    for (int ks = 0; ks < 2; ++ks) {
      short8 pa0 = *(const short8*)&Ps[(q0w + ln15)*72 + ks*32 + hi8];
      short8 pa1 = *(const short8*)&Ps[(q0w + 16 + ln15)*72 + ks*32 + hi8];
      #pragma unroll
      for (int nf = 0; nf < 5; ++nf) {
        short8 bvr = *(const short8*)&Vts[(nf*16 + ln15)*72 + ks*32 + hi8];
        oacc[0][nf] = __builtin_amdgcn_mfma_f32_16x16x32_bf16(pa0, bvr, oacc[0][nf], 0, 0, 0);
        oacc[1][nf] = __builtin_amdgcn_mfma_f32_16x16x32_bf16(pa1, bvr, oacc[1][nf], 0, 0, 0);
      }
    }
  }

  // softmax denominators
  float linv[2][4];
  #pragma unroll
  for (int mf = 0; mf < 2; ++mf)
    #pragma unroll
    for (int j = 0; j < 4; ++j)
      linv[mf][j] = 1.f / __shfl(oacc[mf][4][j], (lane & 48));

  // memory attention via MFMA against M0t (g=1 only)
  f32x4 mfr[2][5];
  #pragma unroll
  for (int mf = 0; mf < 2; ++mf)
    #pragma unroll
    for (int nf = 0; nf < 5; ++nf)
      mfr[mf][nf] = (f32x4){0.f,0.f,0.f,0.f};
  float dinv[2][4] = {};
  if (g) {
    __syncthreads();   // done with Ps as P
    for (int i = tid; i < 640; i += 256) {
      int r = i >> 3, off = (i & 7) * 8;
      *(uint4*)&Ps[r*72 + off] = *(const uint4*)(m0t + (size_t)((b*8+h)*80 + r)*64 + off);
    }
    __syncthreads();
    short8 sqf[2][2];
    #pragma unroll
    for (int mf = 0; mf < 2; ++mf)
      #pragma unroll
      for (int ks = 0; ks < 2; ++ks)
        #pragma unroll
        for (int e = 0; e < 8; ++e) {
          float f = b2f(qf[mf][ks][e]);
          f = f > 0.f ? f + 1.f : __expf(f);
          sqf[mf][ks][e] = f2b(f);
        }
    #pragma unroll
    for (int ks = 0; ks < 2; ++ks)
      #pragma unroll
      for (int nf = 0; nf < 5; ++nf) {
        short8 bmr = *(const short8*)&Ps[(nf*16 + ln15)*72 + ks*32 + hi8];
        mfr[0][nf] = __builtin_amdgcn_mfma_f32_16x16x32_bf16(sqf[0][ks], bmr, mfr[0][nf], 0, 0, 0);
        mfr[1][nf] = __builtin_amdgcn_mfma_f32_16x16x32_bf16(sqf[1][ks], bmr, mfr[1][nf], 0, 0, 0);
      }
    #pragma unroll
    for (int mf = 0; mf < 2; ++mf)
      #pragma unroll
      for (int j = 0; j < 4; ++j)
        dinv[mf][j] = 1.f / __shfl(mfr[mf][4][j], (lane & 48));
  }

  // combine + store
  #pragma unroll
  for (int nf = 0; nf < 4; ++nf) {
    float bt = betas[h*64 + nf*16 + ln15];
    float gt = 1.f / (1.f + __expf(-bt));
    #pragma unroll
    for (int mf = 0; mf < 2; ++mf)
      #pragma unroll
      for (int j = 0; j < 4; ++j) {
        float ad = oacc[mf][nf][j] * linv[mf][j];
        float v = g ? (gt * mfr[mf][nf][j] * dinv[mf][j] + (1.f - gt) * ad)
                    : (1.f - gt) * ad;
        int row = qbase + q0w + mf*16 + (lane>>4)*4 + j;
        att[(size_t)row*512 + h*64 + nf*16 + ln15] = f2b(v);
      }
  }
}

// ---------------- final: x_out = (x + scatter(h)) * pad ----------------
__global__ __launch_bounds__(256) void final_kernel(
    const float* __restrict__ x, const int* __restrict__ inv,
    const float* __restrict__ hm, float* __restrict__ outX)
{
  int row  = blockIdx.x * 4 + (threadIdx.x >> 6);
  int lane = threadIdx.x & 63;
  int b = row >> 14;
  int s = row & (S_TOT - 1);
  size_t base = (size_t)row * DIN + lane * 8;
  if (s >= NUSE * SEGF) {
    float4 z = make_float4(0.f,0.f,0.f,0.f);
    *(float4*)(outX + base)     = z;
    *(float4*)(outX + base + 4) = z;
    return;
  }
  float4 a0 = *(const float4*)(x + base);
  float4 a1 = *(const float4*)(x + base + 4);
  int i = inv[b * (NUSE*SEGF) + s];
  if (i >= 0) {
    size_t hb = (size_t)(b * (NUSE*SEGS) + i) * DIN + lane * 8;
    float4 h0 = *(const float4*)(hm + hb);
    float4 h1 = *(const float4*)(hm + hb + 4);
    a0.x += h0.x; a0.y += h0.y; a0.z += h0.z; a0.w += h0.w;
    a1.x += h1.x; a1.y += h1.y; a1.z += h1.z; a1.w += h1.w;
  }
  *(float4*)(outX + base)     = a0;
  *(float4*)(outX + base + 4) = a1;
}

extern "C" void kernel_launch(void* const* d_in, const int* in_sizes, int n_in,
                              void* d_out, int out_size, void* d_ws, size_t ws_size,
                              hipStream_t stream) {
  (void)in_sizes; (void)n_in; (void)out_size; (void)ws_size;
  const float* x      = (const float*)d_in[0];
  const float* w_samp = (const float*)d_in[1];
  const float* b_samp = (const float*)d_in[2];
  const float* w_q    = (const float*)d_in[3];
  const float* w_k    = (const float*)d_in[4];
  const float* w_v    = (const float*)d_in[5];
  const float* w_o    = (const float*)d_in[6];
  const float* betas  = (const float*)d_in[7];
  const float* w1     = (const float*)d_in[8];
  const float* b1     = (const float*)d_in[9];
  const float* w2     = (const float*)d_in[10];
  const float* b2     = (const float*)d_in[11];

  float* outX      = (float*)d_out;
  float* outMask   = outX + (size_t)BATCH * S_TOT * DIN;
  float* outScores = outMask + (size_t)BATCH * S_TOT;

  char* ws = (char*)d_ws;
  int*   flat  = (int*)(ws);                    // 64 KB
  int*   inv   = (int*)(ws + 65536);            // 64 KB
  int*   flags = (int*)(ws + 131072);           // 256 KB
  short* M0t   = (short*)(ws + 393216);         // [32][80][64] bf16, 320 KB
  short* Wtqkv = (short*)(ws + 1048576);        // [1536][512] bf16, 1.5 MB
  short* Wto   = (short*)(ws + 2621440);        // [512][512], 0.5 MB
  short* Wt1   = (short*)(ws + 3145728);        // [2048][512], 2 MB
  short* Wt2   = (short*)(ws + 5242880);        // [512][2048], 2 MB
  short* xsel  = (short*)(ws + 7340032);        // [4096][512], 4 MB
  short* qkv   = (short*)(ws + 11534336);       // [4096][1536], 12 MB
  short* Vt    = (short*)(ws + 24117248);       // [4][8][64][1024], 4 MB
  short* attb  = (short*)(ws + 28311552);       // [4096][512], 4 MB
  short* R0b   = (short*)(ws + 32505856);       // [4096][512], 4 MB
  short* hidB  = (short*)(ws + 7340032);        // [4096][2048] overlays xsel+qkv
  float* Hf    = (float*)(ws + 24117248);       // [4096][512] f32 overlays Vt+attb

  scores_kernel<<<(BATCH*S_TOT)/4, 256, 0, stream>>>(x, w_samp, b_samp, outScores);
  topk_rank<<<BATCH*NSEG*8, 256, 0, stream>>>(outScores, flags, outMask);
  topk_compact<<<BATCH*NUSE, 256, 0, stream>>>(flags, flat, inv);

  transpose_cast<<<dim3(16,16), 256, 0, stream>>>(w_q, Wtqkv, 512, 512, 0);
  transpose_cast<<<dim3(16,16), 256, 0, stream>>>(w_k, Wtqkv, 512, 512, 512);
  transpose_cast<<<dim3(16,16), 256, 0, stream>>>(w_v, Wtqkv, 512, 512, 1024);
  transpose_cast<<<dim3(16,16), 256, 0, stream>>>(w_o, Wto, 512, 512, 0);
  transpose_cast<<<dim3(64,16), 256, 0, stream>>>(w1, Wt1, 512, 2048, 0);
  transpose_cast<<<dim3(16,64), 256, 0, stream>>>(w2, Wt2, 2048, 512, 0);

  gather_cast<<<MROWS/4, 256, 0, stream>>>(x, flat, xsel);

  gemm_bf16<128,128,64,64><<<dim3(12,32), 256, 0, stream>>>(
      xsel, Wtqkv, nullptr, nullptr, qkv, Vt, MROWS, 1536, 512, 0);

  memsum_t<<<BATCH*NH, 256, 0, stream>>>(qkv, M0t);
  attn3<<<256, 256, 0, stream>>>(qkv, Vt, M0t, betas, attb);

  gemm_bf16<64,128,64,32><<<dim3(4,64), 256, 0, stream>>>(
      attb, Wto, nullptr, nullptr, R0b, nullptr, MROWS, 512, 512, 0);
  gemm_bf16<128,128,64,64><<<dim3(16,32), 256, 0, stream>>>(
      R0b, Wt1, b1, nullptr, hidB, nullptr, MROWS, 2048, 512, 1);
  gemm_bf16<64,128,64,32><<<dim3(4,64), 256, 0, stream>>>(
      hidB, Wt2, b2, Hf, nullptr, nullptr, MROWS, 512, 2048, 0);

  final_kernel<<<(BATCH*S_TOT)/4, 256, 0, stream>>>(x, inv, Hf, outX);
}

// Round 5
// 291.244 us; speedup vs baseline: 6.8437x; 1.0537x over previous
//
#include <hip/hip_runtime.h>
#include <math.h>

#define S_TOT 16384
#define BATCH 4
#define DIN 512
#define NH 8
#define DK 64
#define SEGF 2048
#define SEGS 512
#define NSEG 8
#define NUSE 2
#define MROWS (BATCH*NUSE*SEGS)   // 4096 rows through attention/MLP

typedef unsigned int u32;
typedef __attribute__((ext_vector_type(8))) short short8;
typedef __attribute__((ext_vector_type(4))) float f32x4;

__device__ __forceinline__ short f2b(float f) {
  u32 u = __float_as_uint(f);
  u32 r = u + 0x7fffu + ((u >> 16) & 1u);
  return (short)(r >> 16);
}
__device__ __forceinline__ float b2f(short s) {
  return __uint_as_float(((u32)(unsigned short)s) << 16);
}
__device__ __forceinline__ float b2f_lo(u32 u) { return __uint_as_float(u << 16); }
__device__ __forceinline__ float b2f_hi(u32 u) { return __uint_as_float(u & 0xffff0000u); }

// ---------------- scores = x @ w_samp + b (fp32, exact for routing) ----------------
__global__ __launch_bounds__(256) void scores_kernel(
    const float* __restrict__ x, const float* __restrict__ w,
    const float* __restrict__ bsamp, float* __restrict__ out)
{
  int tok  = blockIdx.x * 4 + (threadIdx.x >> 6);
  int lane = threadIdx.x & 63;
  const float* xr = x + (size_t)tok * DIN;
  float p = 0.f;
  #pragma unroll
  for (int it = 0; it < 8; ++it)
    p += xr[lane + it*64] * w[lane + it*64];
  #pragma unroll
  for (int off = 32; off > 0; off >>= 1) p += __shfl_down(p, off);
  if (lane == 0) out[tok] = p + bsamp[0];
}

// ---------------- topk pass 1: stable rank of every element ----------------
__global__ __launch_bounds__(256) void topk_rank(
    const float* __restrict__ scores, int* __restrict__ flags,
    float* __restrict__ maskOut)
{
  int c = blockIdx.x & 7, g = (blockIdx.x >> 3) & 7, b = blockIdx.x >> 6;
  __shared__ float sc[SEGF];
  int tid = threadIdx.x;
  const float* src = scores + (size_t)b*S_TOT + (size_t)g*SEGF;
  *(float4*)&sc[tid*8]     = *(const float4*)(src + tid*8);
  *(float4*)&sc[tid*8 + 4] = *(const float4*)(src + tid*8 + 4);
  __syncthreads();
  int i0 = c*256 + tid;
  float mine = sc[i0];
  int cnt = 0;
  #pragma unroll 2
  for (int j = 0; j < SEGF; j += 8) {
    float4 a = *(const float4*)&sc[j];
    float4 d = *(const float4*)&sc[j + 4];
    cnt += (a.x > mine || (a.x == mine && (j+0) < i0)) ? 1 : 0;
    cnt += (a.y > mine || (a.y == mine && (j+1) < i0)) ? 1 : 0;
    cnt += (a.z > mine || (a.z == mine && (j+2) < i0)) ? 1 : 0;
    cnt += (a.w > mine || (a.w == mine && (j+3) < i0)) ? 1 : 0;
    cnt += (d.x > mine || (d.x == mine && (j+4) < i0)) ? 1 : 0;
    cnt += (d.y > mine || (d.y == mine && (j+5) < i0)) ? 1 : 0;
    cnt += (d.z > mine || (d.z == mine && (j+6) < i0)) ? 1 : 0;
    cnt += (d.w > mine || (d.w == mine && (j+7) < i0)) ? 1 : 0;
  }
  int flg = (cnt < SEGS) ? 1 : 0;
  flags[(((b << 3) + g) << 11) + i0] = flg;
  maskOut[(size_t)b*S_TOT + (size_t)g*SEGF + i0] = flg ? 1.0f : 0.0f;
}

// ---------------- topk pass 2: compact selected indices (g<NUSE) ----------------
__global__ __launch_bounds__(256) void topk_compact(
    const int* __restrict__ flags, int* __restrict__ flat, int* __restrict__ inv)
{
  int g = blockIdx.x & 1, b = blockIdx.x >> 1;
  __shared__ int wsum[4];
  int tid = threadIdx.x;
  int lane = tid & 63, w = tid >> 6;
  const int* f = flags + (((b << 3) + g) << 11);
  int fl[8]; int ls = 0;
  #pragma unroll
  for (int l = 0; l < 8; ++l) { fl[l] = f[tid*8 + l]; ls += fl[l]; }
  int inc = ls;
  #pragma unroll
  for (int off = 1; off < 64; off <<= 1) {
    int t = __shfl_up(inc, off);
    if (lane >= off) inc += t;
  }
  if (lane == 63) wsum[w] = inc;
  __syncthreads();
  int base = 0;
  #pragma unroll
  for (int ww = 0; ww < 4; ++ww) base += (ww < w) ? wsum[ww] : 0;
  int pos = base + inc - ls;
  #pragma unroll
  for (int l = 0; l < 8; ++l) {
    int i = tid*8 + l;
    inv[b*(NUSE*SEGF) + g*SEGF + i] = fl[l] ? (g*SEGS + pos) : -1;
    if (fl[l]) {
      flat[b*(NSEG*SEGS) + g*SEGS + pos] = g*SEGF + i;
      pos++;
    }
  }
}

// ---------------- transpose+cast weights: src[K][N] fp32 -> dst[(rowoff+n)][k] bf16
__global__ __launch_bounds__(256) void transpose_cast(
    const float* __restrict__ src, short* __restrict__ dst,
    int K, int N, int rowoff)
{
  __shared__ float t[32][33];
  int tid = threadIdx.x;
  int txx = tid & 31, ty = tid >> 5;
  int n0 = blockIdx.x * 32, k0 = blockIdx.y * 32;
  #pragma unroll
  for (int r = 0; r < 4; ++r)
    t[ty + 8*r][txx] = src[(size_t)(k0 + ty + 8*r) * N + n0 + txx];
  __syncthreads();
  #pragma unroll
  for (int r = 0; r < 4; ++r)
    dst[(size_t)(rowoff + n0 + ty + 8*r) * K + k0 + txx] = f2b(t[txx][ty + 8*r]);
}

// ---------------- gather selected rows of x, cast to bf16 ----------------
__global__ __launch_bounds__(256) void gather_cast(
    const float* __restrict__ x, const int* __restrict__ flat,
    short* __restrict__ xsel)
{
  int tok  = blockIdx.x * 4 + (threadIdx.x >> 6);
  int lane = threadIdx.x & 63;
  int b = tok >> 10, i = tok & 1023;
  int gidx = flat[b * (NSEG*SEGS) + i];
  const float* srcp = x + ((size_t)(b * S_TOT + gidx)) * DIN + lane*8;
  float4 a0 = *(const float4*)srcp;
  float4 a1 = *(const float4*)(srcp + 4);
  uint4 o;
  o.x = (u32)(unsigned short)f2b(a0.x) | ((u32)(unsigned short)f2b(a0.y) << 16);
  o.y = (u32)(unsigned short)f2b(a0.z) | ((u32)(unsigned short)f2b(a0.w) << 16);
  o.z = (u32)(unsigned short)f2b(a1.x) | ((u32)(unsigned short)f2b(a1.y) << 16);
  o.w = (u32)(unsigned short)f2b(a1.z) | ((u32)(unsigned short)f2b(a1.w) << 16);
  *(uint4*)(xsel + (size_t)tok * DIN + lane*8) = o;
}

// ---------------- bf16 MFMA GEMM: C[M][N] = act(A[M][K] @ Bt[N][K]^T + bias) -------
// VtOut: optional transposed copy of cols >=1024 (the V block): Vt[b][h][dv][key]
template<int BM, int BN, int WM, int WN>
__global__ __launch_bounds__(256) void gemm_bf16(
    const short* __restrict__ A, const short* __restrict__ Bt,
    const float* __restrict__ bias, float* __restrict__ Cf,
    short* __restrict__ Cb, short* __restrict__ VtOut,
    int M, int N, int K, int act)
{
  constexpr int BK = 32;
  constexpr int WAVES_N = BN / WN;
  constexpr int FM = WM / 16, FN = WN / 16;
  __shared__ short Al[BM * BK];
  __shared__ short Bl[BN * BK];
  const int tid = threadIdx.x;
  const int lane = tid & 63, wid = tid >> 6;
  const int wr = wid / WAVES_N, wc = wid % WAVES_N;
  const int bm = blockIdx.y * BM, bn = blockIdx.x * BN;
  const int srow = tid >> 2;
  const int scol = (tid & 3) * 8;

  f32x4 acc[FM][FN];
  #pragma unroll
  for (int i = 0; i < FM; ++i)
    #pragma unroll
    for (int j = 0; j < FN; ++j)
      #pragma unroll
      for (int e = 0; e < 4; ++e) acc[i][j][e] = 0.f;

  for (int k0 = 0; k0 < K; k0 += BK) {
    __syncthreads();
    #pragma unroll
    for (int i = 0; i < BM/64; ++i) {
      const short* gp = A + (size_t)(bm + i*64 + srow) * K + k0 + scol;
      __builtin_amdgcn_global_load_lds(
          (const __attribute__((address_space(1))) void*)gp,
          (__attribute__((address_space(3))) void*)&Al[(i*64 + srow)*BK + scol],
          16, 0, 0);
    }
    #pragma unroll
    for (int i = 0; i < BN/64; ++i) {
      const short* gp = Bt + (size_t)(bn + i*64 + srow) * K + k0 + scol;
      __builtin_amdgcn_global_load_lds(
          (const __attribute__((address_space(1))) void*)gp,
          (__attribute__((address_space(3))) void*)&Bl[(i*64 + srow)*BK + scol],
          16, 0, 0);
    }
    __syncthreads();
    short8 af[FM], bf_[FN];
    #pragma unroll
    for (int fm = 0; fm < FM; ++fm)
      af[fm] = *(const short8*)&Al[(wr*WM + fm*16 + (lane & 15))*BK + (lane >> 4)*8];
    #pragma unroll
    for (int fn = 0; fn < FN; ++fn)
      bf_[fn] = *(const short8*)&Bl[(wc*WN + fn*16 + (lane & 15))*BK + (lane >> 4)*8];
    #pragma unroll
    for (int fm = 0; fm < FM; ++fm)
      #pragma unroll
      for (int fn = 0; fn < FN; ++fn)
        acc[fm][fn] = __builtin_amdgcn_mfma_f32_16x16x32_bf16(af[fm], bf_[fn], acc[fm][fn], 0, 0, 0);
  }

  const int crow0 = (lane >> 4) * 4, ccol = lane & 15;
  #pragma unroll
  for (int fm = 0; fm < FM; ++fm) {
    #pragma unroll
    for (int fn = 0; fn < FN; ++fn) {
      int c = bn + wc*WN + fn*16 + ccol;
      int r0 = bm + wr*WM + fm*16 + crow0;
      float vv[4];
      #pragma unroll
      for (int j = 0; j < 4; ++j) {
        float v = acc[fm][fn][j];
        if (bias) v += bias[c];
        if (act == 1) v = 0.5f * v * (1.0f + erff(v * 0.70710678118f));
        vv[j] = v;
        if (Cf) Cf[(size_t)(r0 + j) * N + c] = v;
        if (Cb) Cb[(size_t)(r0 + j) * N + c] = f2b(v);
      }
      if (VtOut && c >= 1024) {
        int hh = (c - 1024) >> 6, dv = c & 63;
        int bb = r0 >> 10, key = r0 & 1023;
        u32 lo = (u32)(unsigned short)f2b(vv[0]) | ((u32)(unsigned short)f2b(vv[1]) << 16);
        u32 hi = (u32)(unsigned short)f2b(vv[2]) | ((u32)(unsigned short)f2b(vv[3]) << 16);
        *(uint2*)&VtOut[((size_t)((bb*8 + hh)*64 + dv) << 10) + key] = make_uint2(lo, hi);
      }
    }
  }
}

// ---------------- memsum: Mt[b][h][64][64] bf16 (rows=dv, cols=dk), zf f32[b][h][64]
__global__ __launch_bounds__(256) void memsum_t2(
    const short* __restrict__ qkv, short* __restrict__ m0t, float* __restrict__ zf)
{
  int b = blockIdx.x >> 3, h = blockIdx.x & 7;
  __shared__ float Ks[64][64];
  __shared__ float Vs[64][64];
  int tid = threadIdx.x;
  int tx = tid & 15, ty = tid >> 4;
  int d4 = (tid & 15) * 4, sl = tid >> 4;
  float acc[4][4] = {};
  float zacc[4] = {0.f,0.f,0.f,0.f};
  for (int c = 0; c < 8; ++c) {
    #pragma unroll
    for (int l = 0; l < 4; ++l) {
      int r = c*64 + sl + l*16;
      size_t grow = (size_t)(b*1024 + r) * 1536 + h*64 + d4;
      uint2 kk = *(const uint2*)(qkv + grow + 512);
      float f0 = b2f_lo(kk.x), f1 = b2f_hi(kk.x), f2v = b2f_lo(kk.y), f3 = b2f_hi(kk.y);
      Ks[sl + l*16][d4+0] = f0 > 0.f ? f0 + 1.f : __expf(f0);
      Ks[sl + l*16][d4+1] = f1 > 0.f ? f1 + 1.f : __expf(f1);
      Ks[sl + l*16][d4+2] = f2v > 0.f ? f2v + 1.f : __expf(f2v);
      Ks[sl + l*16][d4+3] = f3 > 0.f ? f3 + 1.f : __expf(f3);
      uint2 vv = *(const uint2*)(qkv + grow + 1024);
      Vs[sl + l*16][d4+0] = b2f_lo(vv.x);
      Vs[sl + l*16][d4+1] = b2f_hi(vv.x);
      Vs[sl + l*16][d4+2] = b2f_lo(vv.y);
      Vs[sl + l*16][d4+3] = b2f_hi(vv.y);
    }
    __syncthreads();
    for (int s2 = 0; s2 < 64; ++s2) {
      float4 a  = *(const float4*)&Ks[s2][ty*4];
      float4 bb = *(const float4*)&Vs[s2][tx*4];
      acc[0][0] += a.x*bb.x; acc[0][1] += a.x*bb.y; acc[0][2] += a.x*bb.z; acc[0][3] += a.x*bb.w;
      acc[1][0] += a.y*bb.x; acc[1][1] += a.y*bb.y; acc[1][2] += a.y*bb.z; acc[1][3] += a.y*bb.w;
      acc[2][0] += a.z*bb.x; acc[2][1] += a.z*bb.y; acc[2][2] += a.z*bb.z; acc[2][3] += a.z*bb.w;
      acc[3][0] += a.w*bb.x; acc[3][1] += a.w*bb.y; acc[3][2] += a.w*bb.z; acc[3][3] += a.w*bb.w;
      if (tx == 0) { zacc[0]+=a.x; zacc[1]+=a.y; zacc[2]+=a.z; zacc[3]+=a.w; }
    }
    __syncthreads();
  }
  size_t mb = (size_t)(b*NH + h) * 4096;
  #pragma unroll
  for (int i = 0; i < 4; ++i)
    #pragma unroll
    for (int j = 0; j < 4; ++j)
      m0t[mb + (size_t)(tx*4 + j)*64 + (ty*4 + i)] = f2b(acc[i][j]);
  if (tx == 0) {
    #pragma unroll
    for (int i = 0; i < 4; ++i)
      zf[(b*NH + h)*64 + ty*4 + i] = 0.015625f + zacc[i];
  }
}

// ---------------- fused MFMA attention v2: proven gload_lds + 2-barrier template ----
// grid 512 = (qt:8, h:8, g:2, b:4); 256 threads = 4 waves; wave owns 16 q rows.
__global__ __launch_bounds__(256) void attn4(
    const short* __restrict__ qkv, const short* __restrict__ vt,
    const short* __restrict__ m0t, const float* __restrict__ zf,
    const float* __restrict__ betas, short* __restrict__ att)
{
  __shared__ short Qs[64*64];       // [q][dk]      8 KB, swizzled
  __shared__ short Ks[128*64];      // [key][dk]   16 KB, swizzled; reused for Mt
  __shared__ short Vts[64*128];     // [dv][key]   16 KB, swizzled
  __shared__ short Ps[4*16*128];    // per-wave P  16 KB, swizzled
  __shared__ float zl[64];
  __shared__ float relay[64];
  int tid = threadIdx.x, lane = tid & 63, w = tid >> 6;
  int ln15 = lane & 15, hi8 = (lane >> 4) * 8;
  int bx = blockIdx.x;
  int qt = bx & 7, h = (bx >> 3) & 7, g = (bx >> 6) & 1, b = bx >> 7;
  const int seg0 = b*1024 + g*512;
  const int qbase = seg0 + qt*64;

  // stage Q once: linear LDS dest, inverse-swizzled global source
  {
    const short* qg = qkv + (size_t)qbase*1536 + h*64;
    #pragma unroll
    for (int p = 0; p < 2; ++p) {
      int slot = p*256 + tid;
      int row = slot >> 3;
      int off = ((slot & 7)*8) ^ ((row & 7)*8);
      __builtin_amdgcn_global_load_lds(
        (const __attribute__((address_space(1))) void*)(qg + (size_t)row*1536 + off),
        (__attribute__((address_space(3))) void*)&Qs[slot*8], 16, 0, 0);
    }
  }
  if (g && tid < 16) *(float4*)&zl[tid*4] = *(const float4*)(zf + (size_t)(b*8+h)*64 + tid*4);
  __syncthreads();

  // Q A-fragments (row = w*16 + ln15)
  short8 qf[2];
  {
    int row = w*16 + ln15;
    #pragma unroll
    for (int ks = 0; ks < 2; ++ks)
      qf[ks] = *(const short8*)&Qs[row*64 + ((ks*32 + hi8) ^ ((row&7)*8))];
  }

  const short* kg = qkv + (size_t)seg0*1536 + 512 + h*64;
  const short* vg = vt + ((size_t)((b*8+h)*64) << 10) + g*512;
  short* Pw = &Ps[w*2048];

  f32x4 oacc[4];
  #pragma unroll
  for (int nf = 0; nf < 4; ++nf) oacc[nf] = (f32x4){0.f,0.f,0.f,0.f};
  float lsum[4] = {0.f,0.f,0.f,0.f};

  for (int c = 0; c < 4; ++c) {
    __syncthreads();   // prior chunk fully consumed
    // stage K chunk: 128 keys x 64 shorts
    #pragma unroll
    for (int p = 0; p < 4; ++p) {
      int slot = p*256 + tid;
      int row = slot >> 3;
      int off = ((slot & 7)*8) ^ ((row & 7)*8);
      __builtin_amdgcn_global_load_lds(
        (const __attribute__((address_space(1))) void*)(kg + (size_t)(c*128 + row)*1536 + off),
        (__attribute__((address_space(3))) void*)&Ks[slot*8], 16, 0, 0);
    }
    // stage Vt chunk: 64 dv x 128 keys
    #pragma unroll
    for (int p = 0; p < 4; ++p) {
      int slot = p*256 + tid;
      int row = slot >> 4;
      int off = ((slot & 15)*8) ^ ((row & 7)*8);
      __builtin_amdgcn_global_load_lds(
        (const __attribute__((address_space(1))) void*)(vg + ((size_t)row << 10) + c*128 + off),
        (__attribute__((address_space(3))) void*)&Vts[slot*8], 16, 0, 0);
    }
    __syncthreads();   // staging visible

    // QK^T: S[16 q][128 keys]
    f32x4 sf[8];
    #pragma unroll
    for (int nf = 0; nf < 8; ++nf) sf[nf] = (f32x4){0.f,0.f,0.f,0.f};
    #pragma unroll
    for (int ks = 0; ks < 2; ++ks)
      #pragma unroll
      for (int nf = 0; nf < 8; ++nf) {
        int row = nf*16 + ln15;
        short8 kb = *(const short8*)&Ks[row*64 + ((ks*32 + hi8) ^ ((row&7)*8))];
        sf[nf] = __builtin_amdgcn_mfma_f32_16x16x32_bf16(qf[ks], kb, sf[nf], 0, 0, 0);
      }
    // P = exp(S/8) -> wave-private LDS (swizzled), accumulate row-sums locally
    #pragma unroll
    for (int nf = 0; nf < 8; ++nf)
      #pragma unroll
      for (int j = 0; j < 4; ++j) {
        float p = __expf(sf[nf][j] * 0.125f);
        lsum[j] += p;
        int q = (lane >> 4)*4 + j;
        int key = nf*16 + ln15;
        Pw[q*128 + (key ^ ((q&7)*8))] = f2b(p);
      }
    // PV += P @ Vt  (k = 128 keys)
    #pragma unroll
    for (int ks = 0; ks < 4; ++ks) {
      short8 pa = *(const short8*)&Pw[ln15*128 + ((ks*32 + hi8) ^ ((ln15&7)*8))];
      #pragma unroll
      for (int nf = 0; nf < 4; ++nf) {
        int row = nf*16 + ln15;
        short8 vb = *(const short8*)&Vts[row*128 + ((ks*32 + hi8) ^ ((row&7)*8))];
        oacc[nf] = __builtin_amdgcn_mfma_f32_16x16x32_bf16(pa, vb, oacc[nf], 0, 0, 0);
      }
    }
  }

  // softmax denominators: reduce over the 16 column-lanes (C layout)
  float linv[4];
  #pragma unroll
  for (int j = 0; j < 4; ++j) {
    float s = lsum[j];
    s += __shfl_xor(s, 1); s += __shfl_xor(s, 2);
    s += __shfl_xor(s, 4); s += __shfl_xor(s, 8);
    linv[j] = 1.f / s;
  }

  // memory attention (g=1): sq @ Mt via MFMA; den = sq . z via shfl + LDS relay
  f32x4 mfr[4];
  #pragma unroll
  for (int nf = 0; nf < 4; ++nf) mfr[nf] = (f32x4){0.f,0.f,0.f,0.f};
  float dinv[4] = {0.f,0.f,0.f,0.f};
  if (g) {
    __syncthreads();   // all waves done reading Ks
    const short* mg = m0t + (size_t)(b*8+h)*4096;
    #pragma unroll
    for (int p = 0; p < 2; ++p) {
      int slot = p*256 + tid;
      int row = slot >> 3;
      int off = ((slot & 7)*8) ^ ((row & 7)*8);
      __builtin_amdgcn_global_load_lds(
        (const __attribute__((address_space(1))) void*)(mg + (size_t)row*64 + off),
        (__attribute__((address_space(3))) void*)&Ks[slot*8], 16, 0, 0);
    }
    __syncthreads();
    // sq = elu(q)+1 from Q fragments
    float sqv[2][8]; short8 sqf[2];
    #pragma unroll
    for (int ks = 0; ks < 2; ++ks)
      #pragma unroll
      for (int e = 0; e < 8; ++e) {
        float f = b2f(qf[ks][e]);
        f = f > 0.f ? f + 1.f : __expf(f);
        sqv[ks][e] = f; sqf[ks][e] = f2b(f);
      }
    float denp = 0.f;
    #pragma unroll
    for (int ks = 0; ks < 2; ++ks)
      #pragma unroll
      for (int e = 0; e < 8; ++e) denp += sqv[ks][e] * zl[ks*32 + hi8 + e];
    denp += __shfl_xor(denp, 16); denp += __shfl_xor(denp, 32);
    if (lane < 16) relay[w*16 + lane] = denp;
    #pragma unroll
    for (int ks = 0; ks < 2; ++ks)
      #pragma unroll
      for (int nf = 0; nf < 4; ++nf) {
        int row = nf*16 + ln15;
        short8 mb_ = *(const short8*)&Ks[row*64 + ((ks*32 + hi8) ^ ((row&7)*8))];
        mfr[nf] = __builtin_amdgcn_mfma_f32_16x16x32_bf16(sqf[ks], mb_, mfr[nf], 0, 0, 0);
      }
    #pragma unroll
    for (int j = 0; j < 4; ++j)
      dinv[j] = 1.f / relay[w*16 + (lane>>4)*4 + j];
  }

  // combine + store
  #pragma unroll
  for (int nf = 0; nf < 4; ++nf) {
    float bt = betas[h*64 + nf*16 + ln15];
    float gt = 1.f / (1.f + __expf(-bt));
    #pragma unroll
    for (int j = 0; j < 4; ++j) {
      float ad = oacc[nf][j] * linv[j];
      float v = g ? (gt * mfr[nf][j] * dinv[j] + (1.f - gt) * ad) : (1.f - gt) * ad;
      int qrow = qbase + w*16 + (lane>>4)*4 + j;
      att[(size_t)qrow*512 + h*64 + nf*16 + ln15] = f2b(v);
    }
  }
}

// ---------------- final: x_out = (x + scatter(h)) * pad ----------------
__global__ __launch_bounds__(256) void final_kernel(
    const float* __restrict__ x, const int* __restrict__ inv,
    const float* __restrict__ hm, float* __restrict__ outX)
{
  int row  = blockIdx.x * 4 + (threadIdx.x >> 6);
  int lane = threadIdx.x & 63;
  int b = row >> 14;
  int s = row & (S_TOT - 1);
  size_t base = (size_t)row * DIN + lane * 8;
  if (s >= NUSE * SEGF) {
    float4 z = make_float4(0.f,0.f,0.f,0.f);
    *(float4*)(outX + base)     = z;
    *(float4*)(outX + base + 4) = z;
    return;
  }
  float4 a0 = *(const float4*)(x + base);
  float4 a1 = *(const float4*)(x + base + 4);
  int i = inv[b * (NUSE*SEGF) + s];
  if (i >= 0) {
    size_t hb = (size_t)(b * (NUSE*SEGS) + i) * DIN + lane * 8;
    float4 h0 = *(const float4*)(hm + hb);
    float4 h1 = *(const float4*)(hm + hb + 4);
    a0.x += h0.x; a0.y += h0.y; a0.z += h0.z; a0.w += h0.w;
    a1.x += h1.x; a1.y += h1.y; a1.z += h1.z; a1.w += h1.w;
  }
  *(float4*)(outX + base)     = a0;
  *(float4*)(outX + base + 4) = a1;
}

extern "C" void kernel_launch(void* const* d_in, const int* in_sizes, int n_in,
                              void* d_out, int out_size, void* d_ws, size_t ws_size,
                              hipStream_t stream) {
  (void)in_sizes; (void)n_in; (void)out_size; (void)ws_size;
  const float* x      = (const float*)d_in[0];
  const float* w_samp = (const float*)d_in[1];
  const float* b_samp = (const float*)d_in[2];
  const float* w_q    = (const float*)d_in[3];
  const float* w_k    = (const float*)d_in[4];
  const float* w_v    = (const float*)d_in[5];
  const float* w_o    = (const float*)d_in[6];
  const float* betas  = (const float*)d_in[7];
  const float* w1     = (const float*)d_in[8];
  const float* b1     = (const float*)d_in[9];
  const float* w2     = (const float*)d_in[10];
  const float* b2     = (const float*)d_in[11];

  float* outX      = (float*)d_out;
  float* outMask   = outX + (size_t)BATCH * S_TOT * DIN;
  float* outScores = outMask + (size_t)BATCH * S_TOT;

  char* ws = (char*)d_ws;
  int*   flat  = (int*)(ws);                    // 64 KB
  int*   inv   = (int*)(ws + 65536);            // 64 KB
  int*   flags = (int*)(ws + 131072);           // 256 KB
  short* M0t   = (short*)(ws + 393216);         // [32][64][64] bf16, 256 KB
  float* Zf    = (float*)(ws + 655360);         // [32][64] f32, 8 KB
  short* Wtqkv = (short*)(ws + 1048576);        // [1536][512] bf16, 1.5 MB
  short* Wto   = (short*)(ws + 2621440);        // [512][512], 0.5 MB
  short* Wt1   = (short*)(ws + 3145728);        // [2048][512], 2 MB
  short* Wt2   = (short*)(ws + 5242880);        // [512][2048], 2 MB
  short* xsel  = (short*)(ws + 7340032);        // [4096][512], 4 MB
  short* qkv   = (short*)(ws + 11534336);       // [4096][1536], 12 MB
  short* Vt    = (short*)(ws + 24117248);       // [4][8][64][1024], 4 MB
  short* attb  = (short*)(ws + 28311552);       // [4096][512], 4 MB
  short* R0b   = (short*)(ws + 32505856);       // [4096][512], 4 MB
  short* hidB  = (short*)(ws + 7340032);        // [4096][2048] overlays xsel+qkv
  float* Hf    = (float*)(ws + 24117248);       // [4096][512] f32 overlays Vt+attb

  scores_kernel<<<(BATCH*S_TOT)/4, 256, 0, stream>>>(x, w_samp, b_samp, outScores);
  topk_rank<<<BATCH*NSEG*8, 256, 0, stream>>>(outScores, flags, outMask);
  topk_compact<<<BATCH*NUSE, 256, 0, stream>>>(flags, flat, inv);

  transpose_cast<<<dim3(16,16), 256, 0, stream>>>(w_q, Wtqkv, 512, 512, 0);
  transpose_cast<<<dim3(16,16), 256, 0, stream>>>(w_k, Wtqkv, 512, 512, 512);
  transpose_cast<<<dim3(16,16), 256, 0, stream>>>(w_v, Wtqkv, 512, 512, 1024);
  transpose_cast<<<dim3(16,16), 256, 0, stream>>>(w_o, Wto, 512, 512, 0);
  transpose_cast<<<dim3(64,16), 256, 0, stream>>>(w1, Wt1, 512, 2048, 0);
  transpose_cast<<<dim3(16,64), 256, 0, stream>>>(w2, Wt2, 2048, 512, 0);

  gather_cast<<<MROWS/4, 256, 0, stream>>>(x, flat, xsel);

  gemm_bf16<128,128,64,64><<<dim3(12,32), 256, 0, stream>>>(
      xsel, Wtqkv, nullptr, nullptr, qkv, Vt, MROWS, 1536, 512, 0);

  memsum_t2<<<BATCH*NH, 256, 0, stream>>>(qkv, M0t, Zf);
  attn4<<<512, 256, 0, stream>>>(qkv, Vt, M0t, Zf, betas, attb);

  gemm_bf16<64,128,64,32><<<dim3(4,64), 256, 0, stream>>>(
      attb, Wto, nullptr, nullptr, R0b, nullptr, MROWS, 512, 512, 0);
  gemm_bf16<128,128,64,64><<<dim3(16,32), 256, 0, stream>>>(
      R0b, Wt1, b1, nullptr, hidB, nullptr, MROWS, 2048, 512, 1);
  gemm_bf16<64,128,64,32><<<dim3(4,64), 256, 0, stream>>>(
      hidB, Wt2, b2, Hf, nullptr, nullptr, MROWS, 512, 2048, 0);

  final_kernel<<<(BATCH*S_TOT)/4, 256, 0, stream>>>(x, inv, Hf, outX);
}

// Round 6
// 255.126 us; speedup vs baseline: 7.8126x; 1.1416x over previous
//
#include <hip/hip_runtime.h>
#include <math.h>

#define S_TOT 16384
#define BATCH 4
#define DIN 512
#define NH 8
#define DK 64
#define SEGF 2048
#define SEGS 512
#define NSEG 8
#define NUSE 2
#define MROWS (BATCH*NUSE*SEGS)   // 4096 rows through attention/MLP

typedef unsigned int u32;
typedef __attribute__((ext_vector_type(8))) short short8;
typedef __attribute__((ext_vector_type(4))) float f32x4;

__device__ __forceinline__ short f2b(float f) {
  u32 u = __float_as_uint(f);
  u32 r = u + 0x7fffu + ((u >> 16) & 1u);
  return (short)(r >> 16);
}
__device__ __forceinline__ float b2f(short s) {
  return __uint_as_float(((u32)(unsigned short)s) << 16);
}
__device__ __forceinline__ float b2f_lo(u32 u) { return __uint_as_float(u << 16); }
__device__ __forceinline__ float b2f_hi(u32 u) { return __uint_as_float(u & 0xffff0000u); }

// ---------------- scores = x @ w_samp + b (fp32, float4 loads) ----------------
__global__ __launch_bounds__(256) void scores_kernel(
    const float* __restrict__ x, const float* __restrict__ w,
    const float* __restrict__ bsamp, float* __restrict__ out)
{
  int tok  = blockIdx.x * 4 + (threadIdx.x >> 6);
  int lane = threadIdx.x & 63;
  const float4* xr = (const float4*)(x + (size_t)tok * DIN);
  const float4* wr = (const float4*)w;
  float4 a0 = xr[lane],      w0 = wr[lane];
  float4 a1 = xr[lane + 64], w1v = wr[lane + 64];
  float p = a0.x*w0.x + a0.y*w0.y + a0.z*w0.z + a0.w*w0.w
          + a1.x*w1v.x + a1.y*w1v.y + a1.z*w1v.z + a1.w*w1v.w;
  #pragma unroll
  for (int off = 32; off > 0; off >>= 1) p += __shfl_down(p, off);
  if (lane == 0) out[tok] = p + bsamp[0];
}

// ---------------- topk pass 1: stable rank of every element ----------------
__global__ __launch_bounds__(256) void topk_rank(
    const float* __restrict__ scores, int* __restrict__ flags,
    float* __restrict__ maskOut)
{
  int c = blockIdx.x & 7, g = (blockIdx.x >> 3) & 7, b = blockIdx.x >> 6;
  __shared__ float sc[SEGF];
  int tid = threadIdx.x;
  const float* src = scores + (size_t)b*S_TOT + (size_t)g*SEGF;
  *(float4*)&sc[tid*8]     = *(const float4*)(src + tid*8);
  *(float4*)&sc[tid*8 + 4] = *(const float4*)(src + tid*8 + 4);
  __syncthreads();
  int i0 = c*256 + tid;
  float mine = sc[i0];
  int cnt = 0;
  #pragma unroll 2
  for (int j = 0; j < SEGF; j += 8) {
    float4 a = *(const float4*)&sc[j];
    float4 d = *(const float4*)&sc[j + 4];
    cnt += (a.x > mine || (a.x == mine && (j+0) < i0)) ? 1 : 0;
    cnt += (a.y > mine || (a.y == mine && (j+1) < i0)) ? 1 : 0;
    cnt += (a.z > mine || (a.z == mine && (j+2) < i0)) ? 1 : 0;
    cnt += (a.w > mine || (a.w == mine && (j+3) < i0)) ? 1 : 0;
    cnt += (d.x > mine || (d.x == mine && (j+4) < i0)) ? 1 : 0;
    cnt += (d.y > mine || (d.y == mine && (j+5) < i0)) ? 1 : 0;
    cnt += (d.z > mine || (d.z == mine && (j+6) < i0)) ? 1 : 0;
    cnt += (d.w > mine || (d.w == mine && (j+7) < i0)) ? 1 : 0;
  }
  int flg = (cnt < SEGS) ? 1 : 0;
  flags[(((b << 3) + g) << 11) + i0] = flg;
  maskOut[(size_t)b*S_TOT + (size_t)g*SEGF + i0] = flg ? 1.0f : 0.0f;
}

// ---------------- topk pass 2: compact selected indices (g<NUSE) ----------------
__global__ __launch_bounds__(256) void topk_compact(
    const int* __restrict__ flags, int* __restrict__ flat, int* __restrict__ inv)
{
  int g = blockIdx.x & 1, b = blockIdx.x >> 1;
  __shared__ int wsum[4];
  int tid = threadIdx.x;
  int lane = tid & 63, w = tid >> 6;
  const int* f = flags + (((b << 3) + g) << 11);
  int fl[8]; int ls = 0;
  #pragma unroll
  for (int l = 0; l < 8; ++l) { fl[l] = f[tid*8 + l]; ls += fl[l]; }
  int inc = ls;
  #pragma unroll
  for (int off = 1; off < 64; off <<= 1) {
    int t = __shfl_up(inc, off);
    if (lane >= off) inc += t;
  }
  if (lane == 63) wsum[w] = inc;
  __syncthreads();
  int base = 0;
  #pragma unroll
  for (int ww = 0; ww < 4; ++ww) base += (ww < w) ? wsum[ww] : 0;
  int pos = base + inc - ls;
  #pragma unroll
  for (int l = 0; l < 8; ++l) {
    int i = tid*8 + l;
    inv[b*(NUSE*SEGF) + g*SEGF + i] = fl[l] ? (g*SEGS + pos) : -1;
    if (fl[l]) {
      flat[b*(NSEG*SEGS) + g*SEGS + pos] = g*SEGF + i;
      pos++;
    }
  }
}

// ---------------- fused transpose+cast of ALL weights in one launch ----------------
// dst[(rowoff+n)][k] = bf16(src[k][n]); 3072 tiles of 32x32
__global__ __launch_bounds__(256) void transpose_all(
    const float* __restrict__ w_q, const float* __restrict__ w_k,
    const float* __restrict__ w_v, const float* __restrict__ w_o,
    const float* __restrict__ w1,  const float* __restrict__ w2,
    short* __restrict__ Wtqkv, short* __restrict__ Wto,
    short* __restrict__ Wt1,   short* __restrict__ Wt2)
{
  __shared__ float t[32][33];
  int bid = blockIdx.x;
  const float* src; short* dst; int K, N, rowoff, tIdx;
  if (bid < 1024) {
    K = 512; N = 512; tIdx = bid & 255;
    int which = bid >> 8;
    src = which == 0 ? w_q : which == 1 ? w_k : which == 2 ? w_v : w_o;
    dst = which == 3 ? Wto : Wtqkv;
    rowoff = which == 3 ? 0 : which * 512;
  } else if (bid < 2048) {
    K = 512; N = 2048; tIdx = bid - 1024; src = w1; dst = Wt1; rowoff = 0;
  } else {
    K = 2048; N = 512; tIdx = bid - 2048; src = w2; dst = Wt2; rowoff = 0;
  }
  int ntN = N >> 5;
  int n0 = (tIdx % ntN) * 32, k0 = (tIdx / ntN) * 32;
  int tid = threadIdx.x;
  int txx = tid & 31, ty = tid >> 5;
  #pragma unroll
  for (int r = 0; r < 4; ++r)
    t[ty + 8*r][txx] = src[(size_t)(k0 + ty + 8*r) * N + n0 + txx];
  __syncthreads();
  #pragma unroll
  for (int r = 0; r < 4; ++r)
    dst[(size_t)(rowoff + n0 + ty + 8*r) * K + k0 + txx] = f2b(t[txx][ty + 8*r]);
}

// ---------------- gather selected rows of x, cast to bf16 ----------------
__global__ __launch_bounds__(256) void gather_cast(
    const float* __restrict__ x, const int* __restrict__ flat,
    short* __restrict__ xsel)
{
  int tok  = blockIdx.x * 4 + (threadIdx.x >> 6);
  int lane = threadIdx.x & 63;
  int b = tok >> 10, i = tok & 1023;
  int gidx = flat[b * (NSEG*SEGS) + i];
  const float* srcp = x + ((size_t)(b * S_TOT + gidx)) * DIN + lane*8;
  float4 a0 = *(const float4*)srcp;
  float4 a1 = *(const float4*)(srcp + 4);
  uint4 o;
  o.x = (u32)(unsigned short)f2b(a0.x) | ((u32)(unsigned short)f2b(a0.y) << 16);
  o.y = (u32)(unsigned short)f2b(a0.z) | ((u32)(unsigned short)f2b(a0.w) << 16);
  o.z = (u32)(unsigned short)f2b(a1.x) | ((u32)(unsigned short)f2b(a1.y) << 16);
  o.w = (u32)(unsigned short)f2b(a1.z) | ((u32)(unsigned short)f2b(a1.w) << 16);
  *(uint4*)(xsel + (size_t)tok * DIN + lane*8) = o;
}

// ---------------- bf16 MFMA GEMM: C[M][N] = act(A[M][K] @ Bt[N][K]^T + bias) -------
// VtOut: cols>=1024 transposed: Vt[b][h][dv][key].  KtOut: cols 512..1023 with
// elu+1 applied, transposed: Kt[b][h][dk][key].
template<int BM, int BN, int WM, int WN>
__global__ __launch_bounds__(256) void gemm_bf16(
    const short* __restrict__ A, const short* __restrict__ Bt,
    const float* __restrict__ bias, float* __restrict__ Cf,
    short* __restrict__ Cb, short* __restrict__ VtOut, short* __restrict__ KtOut,
    int M, int N, int K, int act)
{
  constexpr int BK = 32;
  constexpr int WAVES_N = BN / WN;
  constexpr int FM = WM / 16, FN = WN / 16;
  __shared__ short Al[BM * BK];
  __shared__ short Bl[BN * BK];
  const int tid = threadIdx.x;
  const int lane = tid & 63, wid = tid >> 6;
  const int wr = wid / WAVES_N, wc = wid % WAVES_N;
  const int bm = blockIdx.y * BM, bn = blockIdx.x * BN;
  const int srow = tid >> 2;
  const int scol = (tid & 3) * 8;

  f32x4 acc[FM][FN];
  #pragma unroll
  for (int i = 0; i < FM; ++i)
    #pragma unroll
    for (int j = 0; j < FN; ++j)
      #pragma unroll
      for (int e = 0; e < 4; ++e) acc[i][j][e] = 0.f;

  for (int k0 = 0; k0 < K; k0 += BK) {
    __syncthreads();
    #pragma unroll
    for (int i = 0; i < BM/64; ++i) {
      const short* gp = A + (size_t)(bm + i*64 + srow) * K + k0 + scol;
      __builtin_amdgcn_global_load_lds(
          (const __attribute__((address_space(1))) void*)gp,
          (__attribute__((address_space(3))) void*)&Al[(i*64 + srow)*BK + scol],
          16, 0, 0);
    }
    #pragma unroll
    for (int i = 0; i < BN/64; ++i) {
      const short* gp = Bt + (size_t)(bn + i*64 + srow) * K + k0 + scol;
      __builtin_amdgcn_global_load_lds(
          (const __attribute__((address_space(1))) void*)gp,
          (__attribute__((address_space(3))) void*)&Bl[(i*64 + srow)*BK + scol],
          16, 0, 0);
    }
    __syncthreads();
    short8 af[FM], bf_[FN];
    #pragma unroll
    for (int fm = 0; fm < FM; ++fm)
      af[fm] = *(const short8*)&Al[(wr*WM + fm*16 + (lane & 15))*BK + (lane >> 4)*8];
    #pragma unroll
    for (int fn = 0; fn < FN; ++fn)
      bf_[fn] = *(const short8*)&Bl[(wc*WN + fn*16 + (lane & 15))*BK + (lane >> 4)*8];
    #pragma unroll
    for (int fm = 0; fm < FM; ++fm)
      #pragma unroll
      for (int fn = 0; fn < FN; ++fn)
        acc[fm][fn] = __builtin_amdgcn_mfma_f32_16x16x32_bf16(af[fm], bf_[fn], acc[fm][fn], 0, 0, 0);
  }

  const int crow0 = (lane >> 4) * 4, ccol = lane & 15;
  #pragma unroll
  for (int fm = 0; fm < FM; ++fm) {
    #pragma unroll
    for (int fn = 0; fn < FN; ++fn) {
      int c = bn + wc*WN + fn*16 + ccol;
      int r0 = bm + wr*WM + fm*16 + crow0;
      float vv[4];
      #pragma unroll
      for (int j = 0; j < 4; ++j) {
        float v = acc[fm][fn][j];
        if (bias) v += bias[c];
        if (act == 1) v = 0.5f * v * (1.0f + erff(v * 0.70710678118f));
        vv[j] = v;
        if (Cf) Cf[(size_t)(r0 + j) * N + c] = v;
        if (Cb) Cb[(size_t)(r0 + j) * N + c] = f2b(v);
      }
      if (VtOut && c >= 1024) {
        int hh = (c - 1024) >> 6, dv = c & 63;
        int bb = r0 >> 10, key = r0 & 1023;
        u32 lo = (u32)(unsigned short)f2b(vv[0]) | ((u32)(unsigned short)f2b(vv[1]) << 16);
        u32 hi = (u32)(unsigned short)f2b(vv[2]) | ((u32)(unsigned short)f2b(vv[3]) << 16);
        *(uint2*)&VtOut[((size_t)((bb*8 + hh)*64 + dv) << 10) + key] = make_uint2(lo, hi);
      }
      if (KtOut && c >= 512 && c < 1024) {
        int hh = (c - 512) >> 6, dk = c & 63;
        int bb = r0 >> 10, key = r0 & 1023;
        float e0 = vv[0] > 0.f ? vv[0] + 1.f : __expf(vv[0]);
        float e1 = vv[1] > 0.f ? vv[1] + 1.f : __expf(vv[1]);
        float e2 = vv[2] > 0.f ? vv[2] + 1.f : __expf(vv[2]);
        float e3 = vv[3] > 0.f ? vv[3] + 1.f : __expf(vv[3]);
        u32 lo = (u32)(unsigned short)f2b(e0) | ((u32)(unsigned short)f2b(e1) << 16);
        u32 hi = (u32)(unsigned short)f2b(e2) | ((u32)(unsigned short)f2b(e3) << 16);
        *(uint2*)&KtOut[((size_t)((bb*8 + hh)*64 + dk) << 10) + key] = make_uint2(lo, hi);
      }
    }
  }
}

// ---------------- memsum via MFMA: M0t[b][h][dv][dk] = Vt(seg0) @ Kt(seg0)^T ------
// grid 32 = (b,h); 4 waves; wave w owns dv rows [16w,16w+16); z = rowsum(Kt)
__global__ __launch_bounds__(256) void memsum_mfma(
    const short* __restrict__ Kt, const short* __restrict__ Vt,
    short* __restrict__ m0t, float* __restrict__ zf)
{
  int b = blockIdx.x >> 3, h = blockIdx.x & 7;
  const short* ktb = Kt + ((size_t)((b*8+h)*64) << 10);
  const short* vtb = Vt + ((size_t)((b*8+h)*64) << 10);
  int tid = threadIdx.x, lane = tid & 63, w = tid >> 6;
  int ln15 = lane & 15, hi8 = (lane >> 4) * 8;
  f32x4 acc[4];
  #pragma unroll
  for (int nf = 0; nf < 4; ++nf) acc[nf] = (f32x4){0.f,0.f,0.f,0.f};
  #pragma unroll 4
  for (int ks = 0; ks < 16; ++ks) {
    short8 a = *(const short8*)&vtb[(size_t)(w*16 + ln15)*1024 + ks*32 + hi8];
    #pragma unroll
    for (int nf = 0; nf < 4; ++nf) {
      short8 bfr = *(const short8*)&ktb[(size_t)(nf*16 + ln15)*1024 + ks*32 + hi8];
      acc[nf] = __builtin_amdgcn_mfma_f32_16x16x32_bf16(a, bfr, acc[nf], 0, 0, 0);
    }
  }
  size_t mb = (size_t)(b*NH + h) * 4096;
  #pragma unroll
  for (int nf = 0; nf < 4; ++nf)
    #pragma unroll
    for (int j = 0; j < 4; ++j)
      m0t[mb + (size_t)(w*16 + (lane>>4)*4 + j)*64 + nf*16 + ln15] = f2b(acc[nf][j]);
  // z: row-sums of Kt over first 512 keys; thread = (row, quarter)
  int row = tid >> 2, q = tid & 3;
  float zs = 0.f;
  #pragma unroll 4
  for (int i = 0; i < 16; ++i) {
    short8 kv = *(const short8*)&ktb[(size_t)row*1024 + q*128 + i*8];
    #pragma unroll
    for (int e = 0; e < 8; ++e) zs += b2f(kv[e]);
  }
  zs += __shfl_xor(zs, 1); zs += __shfl_xor(zs, 2);
  if (q == 0) zf[(b*8+h)*64 + row] = 0.015625f + zs;
}

// ---------------- fused MFMA attention: gload_lds + 2-barrier template ----------
// grid 512 = (qt:8, h:8, g:2, b:4); 256 threads = 4 waves; wave owns 16 q rows.
__global__ __launch_bounds__(256) void attn4(
    const short* __restrict__ qkv, const short* __restrict__ vt,
    const short* __restrict__ m0t, const float* __restrict__ zf,
    const float* __restrict__ betas, short* __restrict__ att)
{
  __shared__ short Qs[64*64];       // [q][dk]      8 KB, swizzled
  __shared__ short Ks[128*64];      // [key][dk]   16 KB, swizzled; reused for Mt
  __shared__ short Vts[64*128];     // [dv][key]   16 KB, swizzled
  __shared__ short Ps[4*16*128];    // per-wave P  16 KB, swizzled
  __shared__ float zl[64];
  __shared__ float relay[64];
  int tid = threadIdx.x, lane = tid & 63, w = tid >> 6;
  int ln15 = lane & 15, hi8 = (lane >> 4) * 8;
  int bx = blockIdx.x;
  int qt = bx & 7, h = (bx >> 3) & 7, g = (bx >> 6) & 1, b = bx >> 7;
  const int seg0 = b*1024 + g*512;
  const int qbase = seg0 + qt*64;

  {
    const short* qg = qkv + (size_t)qbase*1536 + h*64;
    #pragma unroll
    for (int p = 0; p < 2; ++p) {
      int slot = p*256 + tid;
      int row = slot >> 3;
      int off = ((slot & 7)*8) ^ ((row & 7)*8);
      __builtin_amdgcn_global_load_lds(
        (const __attribute__((address_space(1))) void*)(qg + (size_t)row*1536 + off),
        (__attribute__((address_space(3))) void*)&Qs[slot*8], 16, 0, 0);
    }
  }
  if (g && tid < 16) *(float4*)&zl[tid*4] = *(const float4*)(zf + (size_t)(b*8+h)*64 + tid*4);
  __syncthreads();

  short8 qf[2];
  {
    int row = w*16 + ln15;
    #pragma unroll
    for (int ks = 0; ks < 2; ++ks)
      qf[ks] = *(const short8*)&Qs[row*64 + ((ks*32 + hi8) ^ ((row&7)*8))];
  }

  const short* kg = qkv + (size_t)seg0*1536 + 512 + h*64;
  const short* vg = vt + ((size_t)((b*8+h)*64) << 10) + g*512;
  short* Pw = &Ps[w*2048];

  f32x4 oacc[4];
  #pragma unroll
  for (int nf = 0; nf < 4; ++nf) oacc[nf] = (f32x4){0.f,0.f,0.f,0.f};
  float lsum[4] = {0.f,0.f,0.f,0.f};

  for (int c = 0; c < 4; ++c) {
    __syncthreads();
    #pragma unroll
    for (int p = 0; p < 4; ++p) {
      int slot = p*256 + tid;
      int row = slot >> 3;
      int off = ((slot & 7)*8) ^ ((row & 7)*8);
      __builtin_amdgcn_global_load_lds(
        (const __attribute__((address_space(1))) void*)(kg + (size_t)(c*128 + row)*1536 + off),
        (__attribute__((address_space(3))) void*)&Ks[slot*8], 16, 0, 0);
    }
    #pragma unroll
    for (int p = 0; p < 4; ++p) {
      int slot = p*256 + tid;
      int row = slot >> 4;
      int off = ((slot & 15)*8) ^ ((row & 7)*8);
      __builtin_amdgcn_global_load_lds(
        (const __attribute__((address_space(1))) void*)(vg + ((size_t)row << 10) + c*128 + off),
        (__attribute__((address_space(3))) void*)&Vts[slot*8], 16, 0, 0);
    }
    __syncthreads();

    f32x4 sf[8];
    #pragma unroll
    for (int nf = 0; nf < 8; ++nf) sf[nf] = (f32x4){0.f,0.f,0.f,0.f};
    #pragma unroll
    for (int ks = 0; ks < 2; ++ks)
      #pragma unroll
      for (int nf = 0; nf < 8; ++nf) {
        int row = nf*16 + ln15;
        short8 kb = *(const short8*)&Ks[row*64 + ((ks*32 + hi8) ^ ((row&7)*8))];
        sf[nf] = __builtin_amdgcn_mfma_f32_16x16x32_bf16(qf[ks], kb, sf[nf], 0, 0, 0);
      }
    #pragma unroll
    for (int nf = 0; nf < 8; ++nf)
      #pragma unroll
      for (int j = 0; j < 4; ++j) {
        float p = __expf(sf[nf][j] * 0.125f);
        lsum[j] += p;
        int q = (lane >> 4)*4 + j;
        int key = nf*16 + ln15;
        Pw[q*128 + (key ^ ((q&7)*8))] = f2b(p);
      }
    #pragma unroll
    for (int ks = 0; ks < 4; ++ks) {
      short8 pa = *(const short8*)&Pw[ln15*128 + ((ks*32 + hi8) ^ ((ln15&7)*8))];
      #pragma unroll
      for (int nf = 0; nf < 4; ++nf) {
        int row = nf*16 + ln15;
        short8 vb = *(const short8*)&Vts[row*128 + ((ks*32 + hi8) ^ ((row&7)*8))];
        oacc[nf] = __builtin_amdgcn_mfma_f32_16x16x32_bf16(pa, vb, oacc[nf], 0, 0, 0);
      }
    }
  }

  float linv[4];
  #pragma unroll
  for (int j = 0; j < 4; ++j) {
    float s = lsum[j];
    s += __shfl_xor(s, 1); s += __shfl_xor(s, 2);
    s += __shfl_xor(s, 4); s += __shfl_xor(s, 8);
    linv[j] = 1.f / s;
  }

  f32x4 mfr[4];
  #pragma unroll
  for (int nf = 0; nf < 4; ++nf) mfr[nf] = (f32x4){0.f,0.f,0.f,0.f};
  float dinv[4] = {0.f,0.f,0.f,0.f};
  if (g) {
    __syncthreads();
    const short* mg = m0t + (size_t)(b*8+h)*4096;
    #pragma unroll
    for (int p = 0; p < 2; ++p) {
      int slot = p*256 + tid;
      int row = slot >> 3;
      int off = ((slot & 7)*8) ^ ((row & 7)*8);
      __builtin_amdgcn_global_load_lds(
        (const __attribute__((address_space(1))) void*)(mg + (size_t)row*64 + off),
        (__attribute__((address_space(3))) void*)&Ks[slot*8], 16, 0, 0);
    }
    __syncthreads();
    float sqv[2][8]; short8 sqf[2];
    #pragma unroll
    for (int ks = 0; ks < 2; ++ks)
      #pragma unroll
      for (int e = 0; e < 8; ++e) {
        float f = b2f(qf[ks][e]);
        f = f > 0.f ? f + 1.f : __expf(f);
        sqv[ks][e] = f; sqf[ks][e] = f2b(f);
      }
    float denp = 0.f;
    #pragma unroll
    for (int ks = 0; ks < 2; ++ks)
      #pragma unroll
      for (int e = 0; e < 8; ++e) denp += sqv[ks][e] * zl[ks*32 + hi8 + e];
    denp += __shfl_xor(denp, 16); denp += __shfl_xor(denp, 32);
    if (lane < 16) relay[w*16 + lane] = denp;
    #pragma unroll
    for (int ks = 0; ks < 2; ++ks)
      #pragma unroll
      for (int nf = 0; nf < 4; ++nf) {
        int row = nf*16 + ln15;
        short8 mb_ = *(const short8*)&Ks[row*64 + ((ks*32 + hi8) ^ ((row&7)*8))];
        mfr[nf] = __builtin_amdgcn_mfma_f32_16x16x32_bf16(sqf[ks], mb_, mfr[nf], 0, 0, 0);
      }
    #pragma unroll
    for (int j = 0; j < 4; ++j)
      dinv[j] = 1.f / relay[w*16 + (lane>>4)*4 + j];
  }

  #pragma unroll
  for (int nf = 0; nf < 4; ++nf) {
    float bt = betas[h*64 + nf*16 + ln15];
    float gt = 1.f / (1.f + __expf(-bt));
    #pragma unroll
    for (int j = 0; j < 4; ++j) {
      float ad = oacc[nf][j] * linv[j];
      float v = g ? (gt * mfr[nf][j] * dinv[j] + (1.f - gt) * ad) : (1.f - gt) * ad;
      int qrow = qbase + w*16 + (lane>>4)*4 + j;
      att[(size_t)qrow*512 + h*64 + nf*16 + ln15] = f2b(v);
    }
  }
}

// ---------------- final: x_out = (x + scatter(h)) * pad ----------------
__global__ __launch_bounds__(256) void final_kernel(
    const float* __restrict__ x, const int* __restrict__ inv,
    const float* __restrict__ hm, float* __restrict__ outX)
{
  int row  = blockIdx.x * 4 + (threadIdx.x >> 6);
  int lane = threadIdx.x & 63;
  int b = row >> 14;
  int s = row & (S_TOT - 1);
  size_t base = (size_t)row * DIN + lane * 8;
  if (s >= NUSE * SEGF) {
    float4 z = make_float4(0.f,0.f,0.f,0.f);
    *(float4*)(outX + base)     = z;
    *(float4*)(outX + base + 4) = z;
    return;
  }
  float4 a0 = *(const float4*)(x + base);
  float4 a1 = *(const float4*)(x + base + 4);
  int i = inv[b * (NUSE*SEGF) + s];
  if (i >= 0) {
    size_t hb = (size_t)(b * (NUSE*SEGS) + i) * DIN + lane * 8;
    float4 h0 = *(const float4*)(hm + hb);
    float4 h1 = *(const float4*)(hm + hb + 4);
    a0.x += h0.x; a0.y += h0.y; a0.z += h0.z; a0.w += h0.w;
    a1.x += h1.x; a1.y += h1.y; a1.z += h1.z; a1.w += h1.w;
  }
  *(float4*)(outX + base)     = a0;
  *(float4*)(outX + base + 4) = a1;
}

extern "C" void kernel_launch(void* const* d_in, const int* in_sizes, int n_in,
                              void* d_out, int out_size, void* d_ws, size_t ws_size,
                              hipStream_t stream) {
  (void)in_sizes; (void)n_in; (void)out_size; (void)ws_size;
  const float* x      = (const float*)d_in[0];
  const float* w_samp = (const float*)d_in[1];
  const float* b_samp = (const float*)d_in[2];
  const float* w_q    = (const float*)d_in[3];
  const float* w_k    = (const float*)d_in[4];
  const float* w_v    = (const float*)d_in[5];
  const float* w_o    = (const float*)d_in[6];
  const float* betas  = (const float*)d_in[7];
  const float* w1     = (const float*)d_in[8];
  const float* b1     = (const float*)d_in[9];
  const float* w2     = (const float*)d_in[10];
  const float* b2     = (const float*)d_in[11];

  float* outX      = (float*)d_out;
  float* outMask   = outX + (size_t)BATCH * S_TOT * DIN;
  float* outScores = outMask + (size_t)BATCH * S_TOT;

  char* ws = (char*)d_ws;
  int*   flat  = (int*)(ws);                    // 64 KB
  int*   inv   = (int*)(ws + 65536);            // 64 KB
  int*   flags = (int*)(ws + 131072);           // 256 KB
  short* M0t   = (short*)(ws + 393216);         // [32][64][64] bf16, 256 KB
  float* Zf    = (float*)(ws + 655360);         // [32][64] f32, 8 KB
  short* Wtqkv = (short*)(ws + 1048576);        // [1536][512] bf16, 1.5 MB
  short* Wto   = (short*)(ws + 2621440);        // [512][512], 0.5 MB
  short* Wt1   = (short*)(ws + 3145728);        // [2048][512], 2 MB
  short* Wt2   = (short*)(ws + 5242880);        // [512][2048], 2 MB
  short* xsel  = (short*)(ws + 7340032);        // [4096][512], 4 MB
  short* qkv   = (short*)(ws + 11534336);       // [4096][1536], 12 MB
  short* Vt    = (short*)(ws + 24117248);       // [4][8][64][1024], 4 MB
  short* attb  = (short*)(ws + 28311552);       // [4096][512], 4 MB
  short* R0b   = (short*)(ws + 32505856);       // [4096][512], 4 MB
  short* Kt    = (short*)(ws + 36700160);       // [4][8][64][1024], 4 MB
  short* hidB  = (short*)(ws + 7340032);        // [4096][2048] overlays xsel+qkv
  float* Hf    = (float*)(ws + 24117248);       // [4096][512] f32 overlays Vt+attb

  scores_kernel<<<(BATCH*S_TOT)/4, 256, 0, stream>>>(x, w_samp, b_samp, outScores);
  topk_rank<<<BATCH*NSEG*8, 256, 0, stream>>>(outScores, flags, outMask);
  topk_compact<<<BATCH*NUSE, 256, 0, stream>>>(flags, flat, inv);

  transpose_all<<<3072, 256, 0, stream>>>(w_q, w_k, w_v, w_o, w1, w2,
                                          Wtqkv, Wto, Wt1, Wt2);

  gather_cast<<<MROWS/4, 256, 0, stream>>>(x, flat, xsel);

  gemm_bf16<128,128,64,64><<<dim3(12,32), 256, 0, stream>>>(
      xsel, Wtqkv, nullptr, nullptr, qkv, Vt, Kt, MROWS, 1536, 512, 0);

  memsum_mfma<<<BATCH*NH, 256, 0, stream>>>(Kt, Vt, M0t, Zf);
  attn4<<<512, 256, 0, stream>>>(qkv, Vt, M0t, Zf, betas, attb);

  gemm_bf16<64,64,32,32><<<dim3(8,64), 256, 0, stream>>>(
      attb, Wto, nullptr, nullptr, R0b, nullptr, nullptr, MROWS, 512, 512, 0);
  gemm_bf16<128,128,64,64><<<dim3(16,32), 256, 0, stream>>>(
      R0b, Wt1, b1, nullptr, hidB, nullptr, nullptr, MROWS, 2048, 512, 1);
  gemm_bf16<64,64,32,32><<<dim3(8,64), 256, 0, stream>>>(
      hidB, Wt2, b2, Hf, nullptr, nullptr, nullptr, MROWS, 512, 2048, 0);

  final_kernel<<<(BATCH*S_TOT)/4, 256, 0, stream>>>(x, inv, Hf, outX);
}

// Round 7
// 247.207 us; speedup vs baseline: 8.0629x; 1.0320x over previous
//
#include <hip/hip_runtime.h>
#include <math.h>

#define S_TOT 16384
#define BATCH 4
#define DIN 512
#define NH 8
#define DK 64
#define SEGF 2048
#define SEGS 512
#define NSEG 8
#define NUSE 2
#define MROWS (BATCH*NUSE*SEGS)   // 4096 rows through attention/MLP

typedef unsigned int u32;
typedef __attribute__((ext_vector_type(8))) short short8;
typedef __attribute__((ext_vector_type(4))) float f32x4;

__device__ __forceinline__ short f2b(float f) {
  u32 u = __float_as_uint(f);
  u32 r = u + 0x7fffu + ((u >> 16) & 1u);
  return (short)(r >> 16);
}
__device__ __forceinline__ float b2f(short s) {
  return __uint_as_float(((u32)(unsigned short)s) << 16);
}
__device__ __forceinline__ float b2f_lo(u32 u) { return __uint_as_float(u << 16); }
__device__ __forceinline__ float b2f_hi(u32 u) { return __uint_as_float(u & 0xffff0000u); }

// ---------------- scores = x @ w_samp + b (fp32, float4 loads) ----------------
__global__ __launch_bounds__(256) void scores_kernel(
    const float* __restrict__ x, const float* __restrict__ w,
    const float* __restrict__ bsamp, float* __restrict__ out)
{
  int tok  = blockIdx.x * 4 + (threadIdx.x >> 6);
  int lane = threadIdx.x & 63;
  const float4* xr = (const float4*)(x + (size_t)tok * DIN);
  const float4* wr = (const float4*)w;
  float4 a0 = xr[lane],      w0 = wr[lane];
  float4 a1 = xr[lane + 64], w1v = wr[lane + 64];
  float p = a0.x*w0.x + a0.y*w0.y + a0.z*w0.z + a0.w*w0.w
          + a1.x*w1v.x + a1.y*w1v.y + a1.z*w1v.z + a1.w*w1v.w;
  #pragma unroll
  for (int off = 32; off > 0; off >>= 1) p += __shfl_down(p, off);
  if (lane == 0) out[tok] = p + bsamp[0];
}

// ---------------- topk pass 1: stable rank of every element ----------------
__global__ __launch_bounds__(256) void topk_rank(
    const float* __restrict__ scores, int* __restrict__ flags,
    float* __restrict__ maskOut)
{
  int c = blockIdx.x & 7, g = (blockIdx.x >> 3) & 7, b = blockIdx.x >> 6;
  __shared__ float sc[SEGF];
  int tid = threadIdx.x;
  const float* src = scores + (size_t)b*S_TOT + (size_t)g*SEGF;
  *(float4*)&sc[tid*8]     = *(const float4*)(src + tid*8);
  *(float4*)&sc[tid*8 + 4] = *(const float4*)(src + tid*8 + 4);
  __syncthreads();
  int i0 = c*256 + tid;
  float mine = sc[i0];
  int cnt = 0;
  #pragma unroll 2
  for (int j = 0; j < SEGF; j += 8) {
    float4 a = *(const float4*)&sc[j];
    float4 d = *(const float4*)&sc[j + 4];
    cnt += (a.x > mine || (a.x == mine && (j+0) < i0)) ? 1 : 0;
    cnt += (a.y > mine || (a.y == mine && (j+1) < i0)) ? 1 : 0;
    cnt += (a.z > mine || (a.z == mine && (j+2) < i0)) ? 1 : 0;
    cnt += (a.w > mine || (a.w == mine && (j+3) < i0)) ? 1 : 0;
    cnt += (d.x > mine || (d.x == mine && (j+4) < i0)) ? 1 : 0;
    cnt += (d.y > mine || (d.y == mine && (j+5) < i0)) ? 1 : 0;
    cnt += (d.z > mine || (d.z == mine && (j+6) < i0)) ? 1 : 0;
    cnt += (d.w > mine || (d.w == mine && (j+7) < i0)) ? 1 : 0;
  }
  int flg = (cnt < SEGS) ? 1 : 0;
  flags[(((b << 3) + g) << 11) + i0] = flg;
  maskOut[(size_t)b*S_TOT + (size_t)g*SEGF + i0] = flg ? 1.0f : 0.0f;
}

// ---------------- topk pass 2: compact selected indices (g<NUSE) ----------------
__global__ __launch_bounds__(256) void topk_compact(
    const int* __restrict__ flags, int* __restrict__ flat, int* __restrict__ inv)
{
  int g = blockIdx.x & 1, b = blockIdx.x >> 1;
  __shared__ int wsum[4];
  int tid = threadIdx.x;
  int lane = tid & 63, w = tid >> 6;
  const int* f = flags + (((b << 3) + g) << 11);
  int fl[8]; int ls = 0;
  #pragma unroll
  for (int l = 0; l < 8; ++l) { fl[l] = f[tid*8 + l]; ls += fl[l]; }
  int inc = ls;
  #pragma unroll
  for (int off = 1; off < 64; off <<= 1) {
    int t = __shfl_up(inc, off);
    if (lane >= off) inc += t;
  }
  if (lane == 63) wsum[w] = inc;
  __syncthreads();
  int base = 0;
  #pragma unroll
  for (int ww = 0; ww < 4; ++ww) base += (ww < w) ? wsum[ww] : 0;
  int pos = base + inc - ls;
  #pragma unroll
  for (int l = 0; l < 8; ++l) {
    int i = tid*8 + l;
    inv[b*(NUSE*SEGF) + g*SEGF + i] = fl[l] ? (g*SEGS + pos) : -1;
    if (fl[l]) {
      flat[b*(NSEG*SEGS) + g*SEGS + pos] = g*SEGF + i;
      pos++;
    }
  }
}

// ---------------- fused transpose+cast of ALL weights in one launch ----------------
__global__ __launch_bounds__(256) void transpose_all(
    const float* __restrict__ w_q, const float* __restrict__ w_k,
    const float* __restrict__ w_v, const float* __restrict__ w_o,
    const float* __restrict__ w1,  const float* __restrict__ w2,
    short* __restrict__ Wtqkv, short* __restrict__ Wto,
    short* __restrict__ Wt1,   short* __restrict__ Wt2)
{
  __shared__ float t[32][33];
  int bid = blockIdx.x;
  const float* src; short* dst; int K, N, rowoff, tIdx;
  if (bid < 1024) {
    K = 512; N = 512; tIdx = bid & 255;
    int which = bid >> 8;
    src = which == 0 ? w_q : which == 1 ? w_k : which == 2 ? w_v : w_o;
    dst = which == 3 ? Wto : Wtqkv;
    rowoff = which == 3 ? 0 : which * 512;
  } else if (bid < 2048) {
    K = 512; N = 2048; tIdx = bid - 1024; src = w1; dst = Wt1; rowoff = 0;
  } else {
    K = 2048; N = 512; tIdx = bid - 2048; src = w2; dst = Wt2; rowoff = 0;
  }
  int ntN = N >> 5;
  int n0 = (tIdx % ntN) * 32, k0 = (tIdx / ntN) * 32;
  int tid = threadIdx.x;
  int txx = tid & 31, ty = tid >> 5;
  #pragma unroll
  for (int r = 0; r < 4; ++r)
    t[ty + 8*r][txx] = src[(size_t)(k0 + ty + 8*r) * N + n0 + txx];
  __syncthreads();
  #pragma unroll
  for (int r = 0; r < 4; ++r)
    dst[(size_t)(rowoff + n0 + ty + 8*r) * K + k0 + txx] = f2b(t[txx][ty + 8*r]);
}

// ---------------- gather selected rows of x, cast to bf16 ----------------
__global__ __launch_bounds__(256) void gather_cast(
    const float* __restrict__ x, const int* __restrict__ flat,
    short* __restrict__ xsel)
{
  int tok  = blockIdx.x * 4 + (threadIdx.x >> 6);
  int lane = threadIdx.x & 63;
  int b = tok >> 10, i = tok & 1023;
  int gidx = flat[b * (NSEG*SEGS) + i];
  const float* srcp = x + ((size_t)(b * S_TOT + gidx)) * DIN + lane*8;
  float4 a0 = *(const float4*)srcp;
  float4 a1 = *(const float4*)(srcp + 4);
  uint4 o;
  o.x = (u32)(unsigned short)f2b(a0.x) | ((u32)(unsigned short)f2b(a0.y) << 16);
  o.y = (u32)(unsigned short)f2b(a0.z) | ((u32)(unsigned short)f2b(a0.w) << 16);
  o.z = (u32)(unsigned short)f2b(a1.x) | ((u32)(unsigned short)f2b(a1.y) << 16);
  o.w = (u32)(unsigned short)f2b(a1.z) | ((u32)(unsigned short)f2b(a1.w) << 16);
  *(uint4*)(xsel + (size_t)tok * DIN + lane*8) = o;
}

// ---------------- bf16 MFMA GEMM, 2-phase double-buffered pipeline --------------
// C[M][N] = act(A[M][K] @ Bt[N][K]^T + bias); optional Vt/Kt transposed epilogues.
template<int BM, int BN, int WM, int WN>
__global__ __launch_bounds__(256) void gemm_bf16(
    const short* __restrict__ A, const short* __restrict__ Bt,
    const float* __restrict__ bias, float* __restrict__ Cf,
    short* __restrict__ Cb, short* __restrict__ VtOut, short* __restrict__ KtOut,
    int M, int N, int K, int act)
{
  constexpr int BK = 32;
  constexpr int WAVES_N = BN / WN;
  constexpr int FM = WM / 16, FN = WN / 16;
  __shared__ short Al[2][BM * BK];
  __shared__ short Bl[2][BN * BK];
  const int tid = threadIdx.x;
  const int lane = tid & 63, wid = tid >> 6;
  const int wr = wid / WAVES_N, wc = wid % WAVES_N;
  const int bm = blockIdx.y * BM, bn = blockIdx.x * BN;
  const int srow = tid >> 2;
  const int scol = (tid & 3) * 8;

  f32x4 acc[FM][FN];
  #pragma unroll
  for (int i = 0; i < FM; ++i)
    #pragma unroll
    for (int j = 0; j < FN; ++j)
      #pragma unroll
      for (int e = 0; e < 4; ++e) acc[i][j][e] = 0.f;

  const int NT = K / BK;

  auto stage = [&](int t, int buf) {
    const int k0 = t * BK;
    #pragma unroll
    for (int i = 0; i < BM/64; ++i) {
      const short* gp = A + (size_t)(bm + i*64 + srow) * K + k0 + scol;
      __builtin_amdgcn_global_load_lds(
          (const __attribute__((address_space(1))) void*)gp,
          (__attribute__((address_space(3))) void*)&Al[buf][(i*64 + srow)*BK + scol],
          16, 0, 0);
    }
    #pragma unroll
    for (int i = 0; i < BN/64; ++i) {
      const short* gp = Bt + (size_t)(bn + i*64 + srow) * K + k0 + scol;
      __builtin_amdgcn_global_load_lds(
          (const __attribute__((address_space(1))) void*)gp,
          (__attribute__((address_space(3))) void*)&Bl[buf][(i*64 + srow)*BK + scol],
          16, 0, 0);
    }
  };

  stage(0, 0);
  __syncthreads();                 // prologue tile resident
  int cur = 0;
  for (int t = 0; t < NT; ++t) {
    if (t + 1 < NT) stage(t + 1, cur ^ 1);   // issue next tile BEFORE compute
    short8 af[FM], bf_[FN];
    #pragma unroll
    for (int fm = 0; fm < FM; ++fm)
      af[fm] = *(const short8*)&Al[cur][(wr*WM + fm*16 + (lane & 15))*BK + (lane >> 4)*8];
    #pragma unroll
    for (int fn = 0; fn < FN; ++fn)
      bf_[fn] = *(const short8*)&Bl[cur][(wc*WN + fn*16 + (lane & 15))*BK + (lane >> 4)*8];
    #pragma unroll
    for (int fm = 0; fm < FM; ++fm)
      #pragma unroll
      for (int fn = 0; fn < FN; ++fn)
        acc[fm][fn] = __builtin_amdgcn_mfma_f32_16x16x32_bf16(af[fm], bf_[fn], acc[fm][fn], 0, 0, 0);
    __syncthreads();               // drains vmcnt: next tile landed; lds reads done
    cur ^= 1;
  }

  const int crow0 = (lane >> 4) * 4, ccol = lane & 15;
  #pragma unroll
  for (int fm = 0; fm < FM; ++fm) {
    #pragma unroll
    for (int fn = 0; fn < FN; ++fn) {
      int c = bn + wc*WN + fn*16 + ccol;
      int r0 = bm + wr*WM + fm*16 + crow0;
      float vv[4];
      #pragma unroll
      for (int j = 0; j < 4; ++j) {
        float v = acc[fm][fn][j];
        if (bias) v += bias[c];
        if (act == 1) v = 0.5f * v * (1.0f + erff(v * 0.70710678118f));
        vv[j] = v;
        if (Cf) Cf[(size_t)(r0 + j) * N + c] = v;
        if (Cb) Cb[(size_t)(r0 + j) * N + c] = f2b(v);
      }
      if (VtOut && c >= 1024) {
        int hh = (c - 1024) >> 6, dv = c & 63;
        int bb = r0 >> 10, key = r0 & 1023;
        u32 lo = (u32)(unsigned short)f2b(vv[0]) | ((u32)(unsigned short)f2b(vv[1]) << 16);
        u32 hi = (u32)(unsigned short)f2b(vv[2]) | ((u32)(unsigned short)f2b(vv[3]) << 16);
        *(uint2*)&VtOut[((size_t)((bb*8 + hh)*64 + dv) << 10) + key] = make_uint2(lo, hi);
      }
      if (KtOut && c >= 512 && c < 1024) {
        int hh = (c - 512) >> 6, dk = c & 63;
        int bb = r0 >> 10, key = r0 & 1023;
        float e0 = vv[0] > 0.f ? vv[0] + 1.f : __expf(vv[0]);
        float e1 = vv[1] > 0.f ? vv[1] + 1.f : __expf(vv[1]);
        float e2 = vv[2] > 0.f ? vv[2] + 1.f : __expf(vv[2]);
        float e3 = vv[3] > 0.f ? vv[3] + 1.f : __expf(vv[3]);
        u32 lo = (u32)(unsigned short)f2b(e0) | ((u32)(unsigned short)f2b(e1) << 16);
        u32 hi = (u32)(unsigned short)f2b(e2) | ((u32)(unsigned short)f2b(e3) << 16);
        *(uint2*)&KtOut[((size_t)((bb*8 + hh)*64 + dk) << 10) + key] = make_uint2(lo, hi);
      }
    }
  }
}

// ---------------- memsum via MFMA: M0t[b][h][dv][dk] = Vt(seg0) @ Kt(seg0)^T ------
__global__ __launch_bounds__(256) void memsum_mfma(
    const short* __restrict__ Kt, const short* __restrict__ Vt,
    short* __restrict__ m0t, float* __restrict__ zf)
{
  int b = blockIdx.x >> 3, h = blockIdx.x & 7;
  const short* ktb = Kt + ((size_t)((b*8+h)*64) << 10);
  const short* vtb = Vt + ((size_t)((b*8+h)*64) << 10);
  int tid = threadIdx.x, lane = tid & 63, w = tid >> 6;
  int ln15 = lane & 15, hi8 = (lane >> 4) * 8;
  f32x4 acc[4];
  #pragma unroll
  for (int nf = 0; nf < 4; ++nf) acc[nf] = (f32x4){0.f,0.f,0.f,0.f};
  #pragma unroll 4
  for (int ks = 0; ks < 16; ++ks) {
    short8 a = *(const short8*)&vtb[(size_t)(w*16 + ln15)*1024 + ks*32 + hi8];
    #pragma unroll
    for (int nf = 0; nf < 4; ++nf) {
      short8 bfr = *(const short8*)&ktb[(size_t)(nf*16 + ln15)*1024 + ks*32 + hi8];
      acc[nf] = __builtin_amdgcn_mfma_f32_16x16x32_bf16(a, bfr, acc[nf], 0, 0, 0);
    }
  }
  size_t mb = (size_t)(b*NH + h) * 4096;
  #pragma unroll
  for (int nf = 0; nf < 4; ++nf)
    #pragma unroll
    for (int j = 0; j < 4; ++j)
      m0t[mb + (size_t)(w*16 + (lane>>4)*4 + j)*64 + nf*16 + ln15] = f2b(acc[nf][j]);
  int row = tid >> 2, q = tid & 3;
  float zs = 0.f;
  #pragma unroll 4
  for (int i = 0; i < 16; ++i) {
    short8 kv = *(const short8*)&ktb[(size_t)row*1024 + q*128 + i*8];
    #pragma unroll
    for (int e = 0; e < 8; ++e) zs += b2f(kv[e]);
  }
  zs += __shfl_xor(zs, 1); zs += __shfl_xor(zs, 2);
  if (q == 0) zf[(b*8+h)*64 + row] = 0.015625f + zs;
}

// ---------------- fused MFMA attention: gload_lds + 2-barrier template ----------
__global__ __launch_bounds__(256) void attn4(
    const short* __restrict__ qkv, const short* __restrict__ vt,
    const short* __restrict__ m0t, const float* __restrict__ zf,
    const float* __restrict__ betas, short* __restrict__ att)
{
  __shared__ short Qs[64*64];
  __shared__ short Ks[128*64];
  __shared__ short Vts[64*128];
  __shared__ short Ps[4*16*128];
  __shared__ float zl[64];
  __shared__ float relay[64];
  int tid = threadIdx.x, lane = tid & 63, w = tid >> 6;
  int ln15 = lane & 15, hi8 = (lane >> 4) * 8;
  int bx = blockIdx.x;
  int qt = bx & 7, h = (bx >> 3) & 7, g = (bx >> 6) & 1, b = bx >> 7;
  const int seg0 = b*1024 + g*512;
  const int qbase = seg0 + qt*64;

  {
    const short* qg = qkv + (size_t)qbase*1536 + h*64;
    #pragma unroll
    for (int p = 0; p < 2; ++p) {
      int slot = p*256 + tid;
      int row = slot >> 3;
      int off = ((slot & 7)*8) ^ ((row & 7)*8);
      __builtin_amdgcn_global_load_lds(
        (const __attribute__((address_space(1))) void*)(qg + (size_t)row*1536 + off),
        (__attribute__((address_space(3))) void*)&Qs[slot*8], 16, 0, 0);
    }
  }
  if (g && tid < 16) *(float4*)&zl[tid*4] = *(const float4*)(zf + (size_t)(b*8+h)*64 + tid*4);
  __syncthreads();

  short8 qf[2];
  {
    int row = w*16 + ln15;
    #pragma unroll
    for (int ks = 0; ks < 2; ++ks)
      qf[ks] = *(const short8*)&Qs[row*64 + ((ks*32 + hi8) ^ ((row&7)*8))];
  }

  const short* kg = qkv + (size_t)seg0*1536 + 512 + h*64;
  const short* vg = vt + ((size_t)((b*8+h)*64) << 10) + g*512;
  short* Pw = &Ps[w*2048];

  f32x4 oacc[4];
  #pragma unroll
  for (int nf = 0; nf < 4; ++nf) oacc[nf] = (f32x4){0.f,0.f,0.f,0.f};
  float lsum[4] = {0.f,0.f,0.f,0.f};

  for (int c = 0; c < 4; ++c) {
    __syncthreads();
    #pragma unroll
    for (int p = 0; p < 4; ++p) {
      int slot = p*256 + tid;
      int row = slot >> 3;
      int off = ((slot & 7)*8) ^ ((row & 7)*8);
      __builtin_amdgcn_global_load_lds(
        (const __attribute__((address_space(1))) void*)(kg + (size_t)(c*128 + row)*1536 + off),
        (__attribute__((address_space(3))) void*)&Ks[slot*8], 16, 0, 0);
    }
    #pragma unroll
    for (int p = 0; p < 4; ++p) {
      int slot = p*256 + tid;
      int row = slot >> 4;
      int off = ((slot & 15)*8) ^ ((row & 7)*8);
      __builtin_amdgcn_global_load_lds(
        (const __attribute__((address_space(1))) void*)(vg + ((size_t)row << 10) + c*128 + off),
        (__attribute__((address_space(3))) void*)&Vts[slot*8], 16, 0, 0);
    }
    __syncthreads();

    f32x4 sf[8];
    #pragma unroll
    for (int nf = 0; nf < 8; ++nf) sf[nf] = (f32x4){0.f,0.f,0.f,0.f};
    #pragma unroll
    for (int ks = 0; ks < 2; ++ks)
      #pragma unroll
      for (int nf = 0; nf < 8; ++nf) {
        int row = nf*16 + ln15;
        short8 kb = *(const short8*)&Ks[row*64 + ((ks*32 + hi8) ^ ((row&7)*8))];
        sf[nf] = __builtin_amdgcn_mfma_f32_16x16x32_bf16(qf[ks], kb, sf[nf], 0, 0, 0);
      }
    #pragma unroll
    for (int nf = 0; nf < 8; ++nf)
      #pragma unroll
      for (int j = 0; j < 4; ++j) {
        float p = __expf(sf[nf][j] * 0.125f);
        lsum[j] += p;
        int q = (lane >> 4)*4 + j;
        int key = nf*16 + ln15;
        Pw[q*128 + (key ^ ((q&7)*8))] = f2b(p);
      }
    #pragma unroll
    for (int ks = 0; ks < 4; ++ks) {
      short8 pa = *(const short8*)&Pw[ln15*128 + ((ks*32 + hi8) ^ ((ln15&7)*8))];
      #pragma unroll
      for (int nf = 0; nf < 4; ++nf) {
        int row = nf*16 + ln15;
        short8 vb = *(const short8*)&Vts[row*128 + ((ks*32 + hi8) ^ ((row&7)*8))];
        oacc[nf] = __builtin_amdgcn_mfma_f32_16x16x32_bf16(pa, vb, oacc[nf], 0, 0, 0);
      }
    }
  }

  float linv[4];
  #pragma unroll
  for (int j = 0; j < 4; ++j) {
    float s = lsum[j];
    s += __shfl_xor(s, 1); s += __shfl_xor(s, 2);
    s += __shfl_xor(s, 4); s += __shfl_xor(s, 8);
    linv[j] = 1.f / s;
  }

  f32x4 mfr[4];
  #pragma unroll
  for (int nf = 0; nf < 4; ++nf) mfr[nf] = (f32x4){0.f,0.f,0.f,0.f};
  float dinv[4] = {0.f,0.f,0.f,0.f};
  if (g) {
    __syncthreads();
    const short* mg = m0t + (size_t)(b*8+h)*4096;
    #pragma unroll
    for (int p = 0; p < 2; ++p) {
      int slot = p*256 + tid;
      int row = slot >> 3;
      int off = ((slot & 7)*8) ^ ((row & 7)*8);
      __builtin_amdgcn_global_load_lds(
        (const __attribute__((address_space(1))) void*)(mg + (size_t)row*64 + off),
        (__attribute__((address_space(3))) void*)&Ks[slot*8], 16, 0, 0);
    }
    __syncthreads();
    float sqv[2][8]; short8 sqf[2];
    #pragma unroll
    for (int ks = 0; ks < 2; ++ks)
      #pragma unroll
      for (int e = 0; e < 8; ++e) {
        float f = b2f(qf[ks][e]);
        f = f > 0.f ? f + 1.f : __expf(f);
        sqv[ks][e] = f; sqf[ks][e] = f2b(f);
      }
    float denp = 0.f;
    #pragma unroll
    for (int ks = 0; ks < 2; ++ks)
      #pragma unroll
      for (int e = 0; e < 8; ++e) denp += sqv[ks][e] * zl[ks*32 + hi8 + e];
    denp += __shfl_xor(denp, 16); denp += __shfl_xor(denp, 32);
    if (lane < 16) relay[w*16 + lane] = denp;
    #pragma unroll
    for (int ks = 0; ks < 2; ++ks)
      #pragma unroll
      for (int nf = 0; nf < 4; ++nf) {
        int row = nf*16 + ln15;
        short8 mb_ = *(const short8*)&Ks[row*64 + ((ks*32 + hi8) ^ ((row&7)*8))];
        mfr[nf] = __builtin_amdgcn_mfma_f32_16x16x32_bf16(sqf[ks], mb_, mfr[nf], 0, 0, 0);
      }
    #pragma unroll
    for (int j = 0; j < 4; ++j)
      dinv[j] = 1.f / relay[w*16 + (lane>>4)*4 + j];
  }

  #pragma unroll
  for (int nf = 0; nf < 4; ++nf) {
    float bt = betas[h*64 + nf*16 + ln15];
    float gt = 1.f / (1.f + __expf(-bt));
    #pragma unroll
    for (int j = 0; j < 4; ++j) {
      float ad = oacc[nf][j] * linv[j];
      float v = g ? (gt * mfr[nf][j] * dinv[j] + (1.f - gt) * ad) : (1.f - gt) * ad;
      int qrow = qbase + w*16 + (lane>>4)*4 + j;
      att[(size_t)qrow*512 + h*64 + nf*16 + ln15] = f2b(v);
    }
  }
}

// ---------------- final: x_out = (x + scatter(h)) * pad ----------------
__global__ __launch_bounds__(256) void final_kernel(
    const float* __restrict__ x, const int* __restrict__ inv,
    const float* __restrict__ hm, float* __restrict__ outX)
{
  int row  = blockIdx.x * 4 + (threadIdx.x >> 6);
  int lane = threadIdx.x & 63;
  int b = row >> 14;
  int s = row & (S_TOT - 1);
  size_t base = (size_t)row * DIN + lane * 8;
  if (s >= NUSE * SEGF) {
    float4 z = make_float4(0.f,0.f,0.f,0.f);
    *(float4*)(outX + base)     = z;
    *(float4*)(outX + base + 4) = z;
    return;
  }
  float4 a0 = *(const float4*)(x + base);
  float4 a1 = *(const float4*)(x + base + 4);
  int i = inv[b * (NUSE*SEGF) + s];
  if (i >= 0) {
    size_t hb = (size_t)(b * (NUSE*SEGS) + i) * DIN + lane * 8;
    float4 h0 = *(const float4*)(hm + hb);
    float4 h1 = *(const float4*)(hm + hb + 4);
    a0.x += h0.x; a0.y += h0.y; a0.z += h0.z; a0.w += h0.w;
    a1.x += h1.x; a1.y += h1.y; a1.z += h1.z; a1.w += h1.w;
  }
  *(float4*)(outX + base)     = a0;
  *(float4*)(outX + base + 4) = a1;
}

extern "C" void kernel_launch(void* const* d_in, const int* in_sizes, int n_in,
                              void* d_out, int out_size, void* d_ws, size_t ws_size,
                              hipStream_t stream) {
  (void)in_sizes; (void)n_in; (void)out_size; (void)ws_size;
  const float* x      = (const float*)d_in[0];
  const float* w_samp = (const float*)d_in[1];
  const float* b_samp = (const float*)d_in[2];
  const float* w_q    = (const float*)d_in[3];
  const float* w_k    = (const float*)d_in[4];
  const float* w_v    = (const float*)d_in[5];
  const float* w_o    = (const float*)d_in[6];
  const float* betas  = (const float*)d_in[7];
  const float* w1     = (const float*)d_in[8];
  const float* b1     = (const float*)d_in[9];
  const float* w2     = (const float*)d_in[10];
  const float* b2     = (const float*)d_in[11];

  float* outX      = (float*)d_out;
  float* outMask   = outX + (size_t)BATCH * S_TOT * DIN;
  float* outScores = outMask + (size_t)BATCH * S_TOT;

  char* ws = (char*)d_ws;
  int*   flat  = (int*)(ws);                    // 64 KB
  int*   inv   = (int*)(ws + 65536);            // 64 KB
  int*   flags = (int*)(ws + 131072);           // 256 KB
  short* M0t   = (short*)(ws + 393216);         // [32][64][64] bf16, 256 KB
  float* Zf    = (float*)(ws + 655360);         // [32][64] f32, 8 KB
  short* Wtqkv = (short*)(ws + 1048576);        // [1536][512] bf16, 1.5 MB
  short* Wto   = (short*)(ws + 2621440);        // [512][512], 0.5 MB
  short* Wt1   = (short*)(ws + 3145728);        // [2048][512], 2 MB
  short* Wt2   = (short*)(ws + 5242880);        // [512][2048], 2 MB
  short* xsel  = (short*)(ws + 7340032);        // [4096][512], 4 MB
  short* qkv   = (short*)(ws + 11534336);       // [4096][1536], 12 MB
  short* Vt    = (short*)(ws + 24117248);       // [4][8][64][1024], 4 MB
  short* attb  = (short*)(ws + 28311552);       // [4096][512], 4 MB
  short* R0b   = (short*)(ws + 32505856);       // [4096][512], 4 MB
  short* Kt    = (short*)(ws + 36700160);       // [4][8][64][1024], 4 MB
  short* hidB  = (short*)(ws + 7340032);        // [4096][2048] overlays xsel+qkv
  float* Hf    = (float*)(ws + 24117248);       // [4096][512] f32 overlays Vt+attb

  scores_kernel<<<(BATCH*S_TOT)/4, 256, 0, stream>>>(x, w_samp, b_samp, outScores);
  topk_rank<<<BATCH*NSEG*8, 256, 0, stream>>>(outScores, flags, outMask);
  topk_compact<<<BATCH*NUSE, 256, 0, stream>>>(flags, flat, inv);

  transpose_all<<<3072, 256, 0, stream>>>(w_q, w_k, w_v, w_o, w1, w2,
                                          Wtqkv, Wto, Wt1, Wt2);

  gather_cast<<<MROWS/4, 256, 0, stream>>>(x, flat, xsel);

  gemm_bf16<128,128,64,64><<<dim3(12,32), 256, 0, stream>>>(
      xsel, Wtqkv, nullptr, nullptr, qkv, Vt, Kt, MROWS, 1536, 512, 0);

  memsum_mfma<<<BATCH*NH, 256, 0, stream>>>(Kt, Vt, M0t, Zf);
  attn4<<<512, 256, 0, stream>>>(qkv, Vt, M0t, Zf, betas, attb);

  gemm_bf16<64,64,32,32><<<dim3(8,64), 256, 0, stream>>>(
      attb, Wto, nullptr, nullptr, R0b, nullptr, nullptr, MROWS, 512, 512, 0);
  gemm_bf16<128,128,64,64><<<dim3(16,32), 256, 0, stream>>>(
      R0b, Wt1, b1, nullptr, hidB, nullptr, nullptr, MROWS, 2048, 512, 1);
  gemm_bf16<64,64,32,32><<<dim3(8,64), 256, 0, stream>>>(
      hidB, Wt2, b2, Hf, nullptr, nullptr, nullptr, MROWS, 512, 2048, 0);

  final_kernel<<<(BATCH*S_TOT)/4, 256, 0, stream>>>(x, inv, Hf, outX);
}